// Round 1
// baseline (4538.818 us; speedup 1.0000x reference)
//
#include <hip/hip_runtime.h>
#include <hip/hip_bf16.h>

#define NNODES 50000
#define NEDGES 800000
#define FDIM   128
#define NCLS   4

// ---------------- degree ----------------
__global__ void k_deg(const int* __restrict__ dst, int* __restrict__ deg) {
    int e = blockIdx.x * blockDim.x + threadIdx.x;
    if (e < NEDGES) atomicAdd(&deg[dst[e]], 1);
}

__global__ void k_inv(const int* __restrict__ deg, float* __restrict__ invd) {
    int n = blockIdx.x * blockDim.x + threadIdx.x;
    if (n < NNODES) {
        int d = deg[n];
        invd[n] = (d > 0) ? (1.0f / (float)d) : 0.0f;
    }
}

// ---------------- scatter-add aggregation ----------------
// 32 threads per edge, float4 each (128 features)
__global__ void k_scatter(const float* __restrict__ feat,
                          const int* __restrict__ src,
                          const int* __restrict__ dst,
                          float* __restrict__ agg) {
    long long tid = (long long)blockIdx.x * blockDim.x + threadIdx.x;
    int e = (int)(tid >> 5);
    int q = (int)(tid & 31);
    if (e >= NEDGES) return;
    int s = src[e];
    int d = dst[e];
    const float4* frow = (const float4*)(feat + (size_t)s * FDIM);
    float4 v = frow[q];
    float* a = agg + (size_t)d * FDIM + q * 4;
    atomicAdd(a + 0, v.x);
    atomicAdd(a + 1, v.y);
    atomicAdd(a + 2, v.z);
    atomicAdd(a + 3, v.w);
}

// ---------------- fused SAGE dense epilogue, 128 outputs ----------------
// out[n,m] = (sum_k agg[n,k]*Wl[k,m]) * invd[n] + bl[m] + sum_k x[n,k]*Wr[k,m]
// block = 256 threads = 2 nodes x 128 features
__global__ void k_sage128(const float* __restrict__ agg,
                          const float* __restrict__ xin,
                          const float* __restrict__ invd,
                          const float* __restrict__ Wl,
                          const float* __restrict__ bl,
                          const float* __restrict__ Wr,
                          float* __restrict__ out,
                          int do_relu) {
    __shared__ float sA[2][FDIM];
    __shared__ float sX[2][FDIM];
    int local = threadIdx.x >> 7;     // 0 or 1
    int m     = threadIdx.x & 127;
    int n     = blockIdx.x * 2 + local;
    sA[local][m] = agg[(size_t)n * FDIM + m];
    sX[local][m] = xin[(size_t)n * FDIM + m];
    __syncthreads();
    float dA = 0.0f, dB = 0.0f;
#pragma unroll 8
    for (int k = 0; k < FDIM; ++k) {
        float wl = Wl[k * FDIM + m];
        float wr = Wr[k * FDIM + m];
        dA = fmaf(sA[local][k], wl, dA);
        dB = fmaf(sX[local][k], wr, dB);
    }
    float r = dA * invd[n] + bl[m] + dB;
    if (do_relu) r = fmaxf(r, 0.0f);
    out[(size_t)n * FDIM + m] = r;
}

// ---------------- final layer, 4 outputs, write twice ----------------
__global__ void k_sage4(const float* __restrict__ agg,
                        const float* __restrict__ h2,
                        const float* __restrict__ invd,
                        const float* __restrict__ Wl,
                        const float* __restrict__ bl,
                        const float* __restrict__ Wr,
                        float* __restrict__ out) {
    int tid = blockIdx.x * blockDim.x + threadIdx.x;
    int n = tid >> 2;
    int c = tid & 3;
    if (n >= NNODES) return;
    const float* arow = agg + (size_t)n * FDIM;
    const float* hrow = h2 + (size_t)n * FDIM;
    float dA = 0.0f, dB = 0.0f;
#pragma unroll 8
    for (int k = 0; k < FDIM; ++k) {
        dA = fmaf(arow[k], Wl[k * NCLS + c], dA);
        dB = fmaf(hrow[k], Wr[k * NCLS + c], dB);
    }
    float r = dA * invd[n] + bl[c] + dB;
    out[(size_t)n * NCLS + c] = r;
    out[(size_t)NNODES * NCLS + (size_t)n * NCLS + c] = r;
}

extern "C" void kernel_launch(void* const* d_in, const int* in_sizes, int n_in,
                              void* d_out, int out_size, void* d_ws, size_t ws_size,
                              hipStream_t stream) {
    const float* x   = (const float*)d_in[0];
    const int* ei    = (const int*)d_in[1];
    const float* Wl0 = (const float*)d_in[2];
    const float* bl0 = (const float*)d_in[3];
    const float* Wr0 = (const float*)d_in[4];
    const float* Wl1 = (const float*)d_in[5];
    const float* bl1 = (const float*)d_in[6];
    const float* Wr1 = (const float*)d_in[7];
    const float* Wl2 = (const float*)d_in[8];
    const float* bl2 = (const float*)d_in[9];
    const float* Wr2 = (const float*)d_in[10];

    const int* src = ei;
    const int* dst = ei + NEDGES;

    float* out = (float*)d_out;                       // [0, 200000): out
                                                      // [200000, 400000): out copy
    float* h2  = out + 2 * (size_t)NNODES * NCLS;     // [400000, +6.4M): h2

    // workspace layout
    char* ws = (char*)d_ws;
    int*   deg  = (int*)ws;                                    // N ints
    float* invd = (float*)(ws + (size_t)NNODES * 4);           // N floats
    float* agg  = (float*)(ws + (size_t)NNODES * 8);           // N*128 floats
    float* h    = (float*)(ws + (size_t)NNODES * 8
                              + (size_t)NNODES * FDIM * 4);    // N*128 floats

    const size_t aggBytes = (size_t)NNODES * FDIM * sizeof(float);

    // degree
    hipMemsetAsync(deg, 0, (size_t)NNODES * sizeof(int), stream);
    k_deg<<<(NEDGES + 255) / 256, 256, 0, stream>>>(dst, deg);
    k_inv<<<(NNODES + 255) / 256, 256, 0, stream>>>(deg, invd);

    const int scatterBlocks = (NEDGES * 32 + 255) / 256;
    const int sageBlocks = NNODES / 2;  // 50000 even

    // layer 0: x -> h (relu)
    hipMemsetAsync(agg, 0, aggBytes, stream);
    k_scatter<<<scatterBlocks, 256, 0, stream>>>(x, src, dst, agg);
    k_sage128<<<sageBlocks, 256, 0, stream>>>(agg, x, invd, Wl0, bl0, Wr0, h, 1);

    // layer 1: h -> h2 (no relu), write into d_out slot
    hipMemsetAsync(agg, 0, aggBytes, stream);
    k_scatter<<<scatterBlocks, 256, 0, stream>>>(h, src, dst, agg);
    k_sage128<<<sageBlocks, 256, 0, stream>>>(agg, h, invd, Wl1, bl1, Wr1, h2, 0);

    // layer 2: h2 -> out (N,4), duplicated
    hipMemsetAsync(agg, 0, aggBytes, stream);
    k_scatter<<<scatterBlocks, 256, 0, stream>>>(h2, src, dst, agg);
    k_sage4<<<(NNODES * NCLS + 255) / 256, 256, 0, stream>>>(agg, h2, invd, Wl2, bl2, Wr2, out);
}

// Round 2
// 426.983 us; speedup vs baseline: 10.6300x; 10.6300x over previous
//
#include <hip/hip_runtime.h>
#include <hip/hip_bf16.h>
#include <stdint.h>

#define NNODES 50000
#define NEDGES 800000
#define FDIM   128
#define NCLS   4
#define SCAN_BLOCKS 196   // ceil(50000/256)

typedef uint32_t u32;
typedef unsigned short u16;

__device__ __forceinline__ u16 f2bf(float f) {
    u32 u = __float_as_uint(f);
    u32 r = u + 0x7fffu + ((u >> 16) & 1u);   // round-to-nearest-even
    return (u16)(r >> 16);
}
__device__ __forceinline__ float bflo(u32 p) { return __uint_as_float(p << 16); }
__device__ __forceinline__ float bfhi(u32 p) { return __uint_as_float(p & 0xffff0000u); }

// ---------------- degree histogram ----------------
__global__ void k_deg(const int* __restrict__ dst, int* __restrict__ deg) {
    int e = blockIdx.x * blockDim.x + threadIdx.x;
    if (e < NEDGES) atomicAdd(&deg[dst[e]], 1);
}

__global__ void k_inv(const int* __restrict__ deg, float* __restrict__ invd) {
    int n = blockIdx.x * blockDim.x + threadIdx.x;
    if (n < NNODES) {
        int d = deg[n];
        invd[n] = (d > 0) ? (1.0f / (float)d) : 0.0f;
    }
}

// ---------------- hierarchical exclusive scan of deg -> offs ----------------
__global__ void k_scan1(const int* __restrict__ deg, int* __restrict__ offs,
                        int* __restrict__ bsum) {
    int t = threadIdx.x;
    int g = blockIdx.x * 256 + t;
    int v = (g < NNODES) ? deg[g] : 0;
    __shared__ int s[256];
    s[t] = v;
    __syncthreads();
    for (int off = 1; off < 256; off <<= 1) {
        int u = (t >= off) ? s[t - off] : 0;
        __syncthreads();
        s[t] += u;
        __syncthreads();
    }
    if (g < NNODES) offs[g] = s[t] - v;        // exclusive
    if (t == 255) bsum[blockIdx.x] = s[255];   // block total
}

__global__ void k_scan2(int* __restrict__ bsum) {
    int t = threadIdx.x;
    int v = (t < SCAN_BLOCKS) ? bsum[t] : 0;
    __shared__ int s[256];
    s[t] = v;
    __syncthreads();
    for (int off = 1; off < 256; off <<= 1) {
        int u = (t >= off) ? s[t - off] : 0;
        __syncthreads();
        s[t] += u;
        __syncthreads();
    }
    if (t < SCAN_BLOCKS) bsum[t] = s[t] - v;   // exclusive
}

__global__ void k_scan3(int* __restrict__ offs, const int* __restrict__ bsum,
                        int* __restrict__ cursor) {
    int g = blockIdx.x * 256 + threadIdx.x;
    if (g < NNODES) {
        int o = offs[g] + bsum[blockIdx.x];
        offs[g] = o;
        cursor[g] = o;
    }
    if (g == 0) offs[NNODES] = NEDGES;
}

// ---------------- CSR bucket fill ----------------
__global__ void k_fill(const int* __restrict__ src, const int* __restrict__ dst,
                       int* __restrict__ cursor, int* __restrict__ csr) {
    int e = blockIdx.x * blockDim.x + threadIdx.x;
    if (e < NEDGES) {
        int d = dst[e];
        int pos = atomicAdd(&cursor[d], 1);
        csr[pos] = src[e];
    }
}

// ---------------- fused dual GEMM: y = in@Wl (bf16), z = in@Wr + b ----------------
// block 256: 8 node-rows staged in LDS; l = t>>7 selects Wl-half vs Wr-half,
// m = t&127 is the output column; 8 accumulators amortize weight loads 8x.
__global__ void k_gemmf(const float* __restrict__ in,
                        const float* __restrict__ Wl,
                        const float* __restrict__ Wr,
                        const float* __restrict__ bias,
                        u16* __restrict__ y,
                        float* __restrict__ z) {
    __shared__ float sx[8][FDIM];
    int t = threadIdx.x;
    int n0 = blockIdx.x * 8;
    const float4* src4 = (const float4*)(in + (size_t)n0 * FDIM);
    ((float4*)&sx[0][0])[t] = src4[t];    // 256 float4 = 8 rows x 128
    __syncthreads();
    int l = t >> 7;
    int m = t & 127;
    const float* W = l ? Wr : Wl;
    float acc[8] = {0, 0, 0, 0, 0, 0, 0, 0};
#pragma unroll 4
    for (int k = 0; k < FDIM; ++k) {
        float w = W[k * FDIM + m];
#pragma unroll
        for (int j = 0; j < 8; ++j) acc[j] = fmaf(sx[j][k], w, acc[j]);
    }
    if (l == 0) {
#pragma unroll
        for (int j = 0; j < 8; ++j) y[(size_t)(n0 + j) * FDIM + m] = f2bf(acc[j]);
    } else {
        float b = bias[m];
#pragma unroll
        for (int j = 0; j < 8; ++j) z[(size_t)(n0 + j) * FDIM + m] = acc[j] + b;
    }
}

// ---------------- gather aggregation + epilogue (128-wide) ----------------
// 16 lanes per node, 8 bf16 features per lane (uint4 = 16B load per neighbor).
// io holds z = in@Wr + b on entry; exits as invd*sum(y[nbrs]) + z (+relu).
template <int RELU>
__global__ void k_agg(const u16* __restrict__ y,
                      const int* __restrict__ offs,
                      const int* __restrict__ csr,
                      const float* __restrict__ invd,
                      float* __restrict__ io) {
    int t = threadIdx.x;
    int nl = t >> 4, q = t & 15;
    int n = blockIdx.x * 16 + nl;
    int beg = offs[n], end = offs[n + 1];
    float a0 = 0, a1 = 0, a2 = 0, a3 = 0, a4 = 0, a5 = 0, a6 = 0, a7 = 0;
    const u16* yq = y + (size_t)q * 8;
    for (int i = beg; i < end; ++i) {
        int s = csr[i];
        uint4 v = *(const uint4*)(yq + (size_t)s * FDIM);
        a0 += bflo(v.x); a1 += bfhi(v.x);
        a2 += bflo(v.y); a3 += bfhi(v.y);
        a4 += bflo(v.z); a5 += bfhi(v.z);
        a6 += bflo(v.w); a7 += bfhi(v.w);
    }
    float iv = invd[n];
    float* o = io + (size_t)n * FDIM + q * 8;
    float4 z0 = ((float4*)o)[0], z1 = ((float4*)o)[1];
    float4 r0, r1;
    r0.x = fmaf(a0, iv, z0.x); r0.y = fmaf(a1, iv, z0.y);
    r0.z = fmaf(a2, iv, z0.z); r0.w = fmaf(a3, iv, z0.w);
    r1.x = fmaf(a4, iv, z1.x); r1.y = fmaf(a5, iv, z1.y);
    r1.z = fmaf(a6, iv, z1.z); r1.w = fmaf(a7, iv, z1.w);
    if (RELU) {
        r0.x = fmaxf(r0.x, 0.f); r0.y = fmaxf(r0.y, 0.f);
        r0.z = fmaxf(r0.z, 0.f); r0.w = fmaxf(r0.w, 0.f);
        r1.x = fmaxf(r1.x, 0.f); r1.y = fmaxf(r1.y, 0.f);
        r1.z = fmaxf(r1.z, 0.f); r1.w = fmaxf(r1.w, 0.f);
    }
    ((float4*)o)[0] = r0;
    ((float4*)o)[1] = r1;
}

// ---------------- layer 2 transform: y4 = h2@Wl2, out = h2@Wr2 + b ----------------
__global__ void k_gemm4(const float* __restrict__ h2,
                        const float* __restrict__ Wl,
                        const float* __restrict__ Wr,
                        const float* __restrict__ bias,
                        float* __restrict__ y4,
                        float* __restrict__ outz) {
    int tid = blockIdx.x * blockDim.x + threadIdx.x;
    int n = tid >> 2, c = tid & 3;
    if (n >= NNODES) return;
    const float4* row = (const float4*)(h2 + (size_t)n * FDIM);
    float a = 0, b = 0;
#pragma unroll 8
    for (int k4 = 0; k4 < 32; ++k4) {
        float4 v = row[k4];
        int k = k4 * 4;
        a = fmaf(v.x, Wl[(k + 0) * 4 + c], a); b = fmaf(v.x, Wr[(k + 0) * 4 + c], b);
        a = fmaf(v.y, Wl[(k + 1) * 4 + c], a); b = fmaf(v.y, Wr[(k + 1) * 4 + c], b);
        a = fmaf(v.z, Wl[(k + 2) * 4 + c], a); b = fmaf(v.z, Wr[(k + 2) * 4 + c], b);
        a = fmaf(v.w, Wl[(k + 3) * 4 + c], a); b = fmaf(v.w, Wr[(k + 3) * 4 + c], b);
    }
    y4[(size_t)n * 4 + c] = a;
    outz[(size_t)n * 4 + c] = b + bias[c];
}

// ---------------- layer 2 aggregation (4-wide) + duplicate write ----------------
__global__ void k_agg4(const float* __restrict__ y4,
                       const int* __restrict__ offs,
                       const int* __restrict__ csr,
                       const float* __restrict__ invd,
                       float* __restrict__ out) {
    int tid = blockIdx.x * blockDim.x + threadIdx.x;
    int n = tid >> 2, c = tid & 3;
    if (n >= NNODES) return;
    int beg = offs[n], end = offs[n + 1];
    float acc = 0;
    for (int i = beg; i < end; ++i) acc += y4[(size_t)csr[i] * 4 + c];
    float r = fmaf(acc, invd[n], out[(size_t)n * 4 + c]);
    out[(size_t)n * 4 + c] = r;
    out[(size_t)NNODES * NCLS + (size_t)n * 4 + c] = r;
}

extern "C" void kernel_launch(void* const* d_in, const int* in_sizes, int n_in,
                              void* d_out, int out_size, void* d_ws, size_t ws_size,
                              hipStream_t stream) {
    const float* x   = (const float*)d_in[0];
    const int* ei    = (const int*)d_in[1];
    const float* Wl0 = (const float*)d_in[2];
    const float* bl0 = (const float*)d_in[3];
    const float* Wr0 = (const float*)d_in[4];
    const float* Wl1 = (const float*)d_in[5];
    const float* bl1 = (const float*)d_in[6];
    const float* Wr1 = (const float*)d_in[7];
    const float* Wl2 = (const float*)d_in[8];
    const float* bl2 = (const float*)d_in[9];
    const float* Wr2 = (const float*)d_in[10];

    const int* src = ei;
    const int* dst = ei + NEDGES;

    float* out = (float*)d_out;
    float* h2  = out + 2 * (size_t)NNODES * NCLS;   // [N,128] lives in d_out

    // workspace layout (all offsets 256B-aligned), total ~43 MB
    char* ws = (char*)d_ws;
    int*   offs   = (int*)(ws + 0);            // (N+1) ints
    int*   degc   = (int*)(ws + 200192);       // N ints: histogram, then cursor
    float* invd   = (float*)(ws + 400384);     // N floats
    int*   bsum   = (int*)(ws + 600576);       // 256 ints
    int*   csr    = (int*)(ws + 601600);       // E ints
    u16*   y      = (u16*)(ws + 3801600);      // N*128 bf16
    float* y4     = (float*)(ws + 16601600);   // N*4 floats
    float* h      = (float*)(ws + 17401600);   // N*128 floats

    // ---- graph structure (CSR) ----
    hipMemsetAsync(degc, 0, (size_t)NNODES * sizeof(int), stream);
    k_deg<<<(NEDGES + 255) / 256, 256, 0, stream>>>(dst, degc);
    k_inv<<<SCAN_BLOCKS, 256, 0, stream>>>(degc, invd);
    k_scan1<<<SCAN_BLOCKS, 256, 0, stream>>>(degc, offs, bsum);
    k_scan2<<<1, 256, 0, stream>>>(bsum);
    k_scan3<<<SCAN_BLOCKS, 256, 0, stream>>>(offs, bsum, degc);
    k_fill<<<(NEDGES + 255) / 256, 256, 0, stream>>>(src, dst, degc, csr);

    // ---- layer 0: x -> h (relu) ----
    k_gemmf<<<NNODES / 8, 256, 0, stream>>>(x, Wl0, Wr0, bl0, y, h);
    k_agg<1><<<NNODES / 16, 256, 0, stream>>>(y, offs, csr, invd, h);

    // ---- layer 1: h -> h2 ----
    k_gemmf<<<NNODES / 8, 256, 0, stream>>>(h, Wl1, Wr1, bl1, y, h2);
    k_agg<0><<<NNODES / 16, 256, 0, stream>>>(y, offs, csr, invd, h2);

    // ---- layer 2: h2 -> out [N,4], duplicated ----
    k_gemm4<<<(NNODES * NCLS + 255) / 256, 256, 0, stream>>>(h2, Wl2, Wr2, bl2, y4, out);
    k_agg4<<<(NNODES * NCLS + 255) / 256, 256, 0, stream>>>(y4, offs, csr, invd, out);
}

// Round 3
// 361.378 us; speedup vs baseline: 12.5597x; 1.1815x over previous
//
#include <hip/hip_runtime.h>
#include <hip/hip_bf16.h>
#include <stdint.h>

#define NNODES 50000
#define NEDGES 800000
#define FDIM   128
#define NCLS   4
#define SCAN_BLOCKS 196   // ceil(50000/256)
#define LPITCH 136        // LDS row pitch in bf16 elements (272B: +8 pad kills bank conflicts)

typedef uint32_t u32;
typedef unsigned short u16;
typedef __bf16 bf16x8 __attribute__((ext_vector_type(8)));
typedef float f32x4 __attribute__((ext_vector_type(4)));

__device__ __forceinline__ u16 f2bf(float f) {
    u32 u = __float_as_uint(f);
    u32 r = u + 0x7fffu + ((u >> 16) & 1u);   // round-to-nearest-even
    return (u16)(r >> 16);
}
__device__ __forceinline__ u32 pack2(float a, float b) {
    return (u32)f2bf(a) | ((u32)f2bf(b) << 16);
}
__device__ __forceinline__ float bflo(u32 p) { return __uint_as_float(p << 16); }
__device__ __forceinline__ float bfhi(u32 p) { return __uint_as_float(p & 0xffff0000u); }

// ---------------- degree histogram ----------------
__global__ void k_deg(const int* __restrict__ dst, int* __restrict__ deg) {
    int e = blockIdx.x * blockDim.x + threadIdx.x;
    if (e < NEDGES) atomicAdd(&deg[dst[e]], 1);
}

__global__ void k_inv(const int* __restrict__ deg, float* __restrict__ invd) {
    int n = blockIdx.x * blockDim.x + threadIdx.x;
    if (n < NNODES) {
        int d = deg[n];
        invd[n] = (d > 0) ? (1.0f / (float)d) : 0.0f;
    }
}

// ---------------- hierarchical exclusive scan of deg -> offs ----------------
__global__ void k_scan1(const int* __restrict__ deg, int* __restrict__ offs,
                        int* __restrict__ bsum) {
    int t = threadIdx.x;
    int g = blockIdx.x * 256 + t;
    int v = (g < NNODES) ? deg[g] : 0;
    __shared__ int s[256];
    s[t] = v;
    __syncthreads();
    for (int off = 1; off < 256; off <<= 1) {
        int u = (t >= off) ? s[t - off] : 0;
        __syncthreads();
        s[t] += u;
        __syncthreads();
    }
    if (g < NNODES) offs[g] = s[t] - v;        // exclusive
    if (t == 255) bsum[blockIdx.x] = s[255];   // block total
}

__global__ void k_scan2(int* __restrict__ bsum) {
    int t = threadIdx.x;
    int v = (t < SCAN_BLOCKS) ? bsum[t] : 0;
    __shared__ int s[256];
    s[t] = v;
    __syncthreads();
    for (int off = 1; off < 256; off <<= 1) {
        int u = (t >= off) ? s[t - off] : 0;
        __syncthreads();
        s[t] += u;
        __syncthreads();
    }
    if (t < SCAN_BLOCKS) bsum[t] = s[t] - v;   // exclusive
}

__global__ void k_scan3(int* __restrict__ offs, const int* __restrict__ bsum,
                        int* __restrict__ cursor) {
    int g = blockIdx.x * 256 + threadIdx.x;
    if (g < NNODES) {
        int o = offs[g] + bsum[blockIdx.x];
        offs[g] = o;
        cursor[g] = o;
    }
    if (g == 0) offs[NNODES] = NEDGES;
}

// ---------------- CSR bucket fill ----------------
__global__ void k_fill(const int* __restrict__ src, const int* __restrict__ dst,
                       int* __restrict__ cursor, int* __restrict__ csr) {
    int e = blockIdx.x * blockDim.x + threadIdx.x;
    if (e < NEDGES) {
        int d = dst[e];
        int pos = atomicAdd(&cursor[d], 1);
        csr[pos] = src[e];
    }
}

// ---------------- fp32 -> bf16 cast (x input), 8 elems/thread ----------------
__global__ void k_cast(const float* __restrict__ in, u16* __restrict__ out) {
    int i = blockIdx.x * 256 + threadIdx.x;    // 800000 threads total
    const float4* p = (const float4*)in + (size_t)i * 2;
    float4 a = p[0], b = p[1];
    uint4 r;
    r.x = pack2(a.x, a.y); r.y = pack2(a.z, a.w);
    r.z = pack2(b.x, b.y); r.w = pack2(b.z, b.w);
    ((uint4*)out)[i] = r;
}

// ---------------- weight pack: [Wl|Wr] fp32 -> bf16 MFMA B-fragment layout ---
// Bp flat layout: [nt(16)][ks(4)][lane(64)][j(8)], value = Wcat[k][col]
// col = nt*16 + (lane&15), k = ks*32 + (lane>>4)*8 + j
__global__ void k_pack(const float* __restrict__ Wl, const float* __restrict__ Wr,
                       u16* __restrict__ Bp) {
    int tid = blockIdx.x * 256 + threadIdx.x;  // 0..32767
    int j    = tid & 7;
    int lane = (tid >> 3) & 63;
    int ks   = (tid >> 9) & 3;
    int nt   = tid >> 11;
    int col  = nt * 16 + (lane & 15);
    int k    = ks * 32 + (lane >> 4) * 8 + j;
    float v = (col < FDIM) ? Wl[k * FDIM + col] : Wr[k * FDIM + (col - FDIM)];
    Bp[tid] = f2bf(v);
}

// ---------------- MFMA dual GEMM: y = in@Wl (bf16), zb = in@Wr + b (bf16) ----
// Block = 256 thr (4 waves), 64 rows/block. Wave w owns cols [w*64, w*64+64):
// waves 0,1 -> y half; waves 2,3 -> z half (uniform, no divergence).
// Each wave: 4 M-tiles x 4 N-tiles x 4 K-steps of mfma_f32_16x16x32_bf16.
__global__ void __launch_bounds__(256) k_mfma(
        const u16* __restrict__ inb,      // [N][128] bf16
        const uint4* __restrict__ Bp,     // packed fragments
        const float* __restrict__ bias,   // [128]
        u16* __restrict__ y,              // [N][128] bf16
        u16* __restrict__ zb) {           // [N][128] bf16
    __shared__ u16 sA[64 * LPITCH];
    int t = threadIdx.x;
    int blk = blockIdx.x;

    // stage A-tile: 64 rows x 128 bf16 (16 uint4 per row, 4 threads/row)
    {
        int row = t >> 2;
        int g4  = (t & 3) * 4;
        int r = blk * 64 + row;
        if (r >= NNODES) r = NNODES - 1;   // clamp; results for pad rows unused
        const uint4* gsrc = (const uint4*)(inb + (size_t)r * FDIM);
        uint4* ldst = (uint4*)(sA + row * LPITCH);   // byte offset row*272, 16B-aligned
#pragma unroll
        for (int i = 0; i < 4; ++i) ldst[g4 + i] = gsrc[g4 + i];
    }
    __syncthreads();

    int wave = t >> 6;
    int lane = t & 63;
    int m    = lane & 15;
    int quad = lane >> 4;

    // A fragments: a[mt][ks] covers rows mt*16+m, k = ks*32 + quad*8 + j
    bf16x8 a[4][4];
#pragma unroll
    for (int mt = 0; mt < 4; ++mt)
#pragma unroll
        for (int ks = 0; ks < 4; ++ks) {
            const uint4* ap = (const uint4*)(sA + (mt * 16 + m) * LPITCH + ks * 32 + quad * 8);
            a[mt][ks] = __builtin_bit_cast(bf16x8, *ap);
        }

    f32x4 acc[4][4];   // [mt][nt]
#pragma unroll
    for (int mt = 0; mt < 4; ++mt)
#pragma unroll
        for (int nt = 0; nt < 4; ++nt) acc[mt][nt] = (f32x4){0.f, 0.f, 0.f, 0.f};

#pragma unroll
    for (int ks = 0; ks < 4; ++ks) {
#pragma unroll
        for (int nt = 0; nt < 4; ++nt) {
            int ntg = wave * 4 + nt;
            bf16x8 b = __builtin_bit_cast(bf16x8, Bp[(ntg * 4 + ks) * 64 + lane]);
#pragma unroll
            for (int mt = 0; mt < 4; ++mt)
                acc[mt][nt] = __builtin_amdgcn_mfma_f32_16x16x32_bf16(
                    a[mt][ks], b, acc[mt][nt], 0, 0, 0);
        }
    }

    // epilogue: C/D layout col=lane&15, row=quad*4+reg
#pragma unroll
    for (int nt = 0; nt < 4; ++nt) {
        int ntg = wave * 4 + nt;
        int col = ntg * 16 + m;
#pragma unroll
        for (int mt = 0; mt < 4; ++mt) {
            int grow = blk * 64 + mt * 16 + quad * 4;
#pragma unroll
            for (int r = 0; r < 4; ++r) {
                int gr = grow + r;
                if (gr < NNODES) {
                    if (col < FDIM) {
                        y[(size_t)gr * FDIM + col] = f2bf(acc[mt][nt][r]);
                    } else {
                        float bv = bias[col - FDIM];
                        zb[(size_t)gr * FDIM + (col - FDIM)] = f2bf(acc[mt][nt][r] + bv);
                    }
                }
            }
        }
    }
}

// ---------------- gather aggregation + epilogue (128-wide) ----------------
// 16 lanes per node, 8 bf16 features per lane. out = invd*sum(y[nbrs]) + zb (+relu)
template <int RELU, int OUTBF>
__global__ void k_agg(const u16* __restrict__ y,
                      const int* __restrict__ offs,
                      const int* __restrict__ csr,
                      const float* __restrict__ invd,
                      const u16* __restrict__ zb,
                      u16* __restrict__ outb,
                      float* __restrict__ outf) {
    int t = threadIdx.x;
    int nl = t >> 4, q = t & 15;
    int n = blockIdx.x * 16 + nl;
    int beg = offs[n], end = offs[n + 1];
    float a0 = 0, a1 = 0, a2 = 0, a3 = 0, a4 = 0, a5 = 0, a6 = 0, a7 = 0;
    const u16* yq = y + (size_t)q * 8;
    for (int i = beg; i < end; ++i) {
        int s = csr[i];
        uint4 v = *(const uint4*)(yq + (size_t)s * FDIM);
        a0 += bflo(v.x); a1 += bfhi(v.x);
        a2 += bflo(v.y); a3 += bfhi(v.y);
        a4 += bflo(v.z); a5 += bfhi(v.z);
        a6 += bflo(v.w); a7 += bfhi(v.w);
    }
    float iv = invd[n];
    uint4 zv = *(const uint4*)(zb + (size_t)n * FDIM + q * 8);
    float r0 = fmaf(a0, iv, bflo(zv.x)), r1 = fmaf(a1, iv, bfhi(zv.x));
    float r2 = fmaf(a2, iv, bflo(zv.y)), r3 = fmaf(a3, iv, bfhi(zv.y));
    float r4 = fmaf(a4, iv, bflo(zv.z)), r5 = fmaf(a5, iv, bfhi(zv.z));
    float r6 = fmaf(a6, iv, bflo(zv.w)), r7 = fmaf(a7, iv, bfhi(zv.w));
    if (RELU) {
        r0 = fmaxf(r0, 0.f); r1 = fmaxf(r1, 0.f); r2 = fmaxf(r2, 0.f); r3 = fmaxf(r3, 0.f);
        r4 = fmaxf(r4, 0.f); r5 = fmaxf(r5, 0.f); r6 = fmaxf(r6, 0.f); r7 = fmaxf(r7, 0.f);
    }
    if (OUTBF) {
        uint4 o;
        o.x = pack2(r0, r1); o.y = pack2(r2, r3);
        o.z = pack2(r4, r5); o.w = pack2(r6, r7);
        *(uint4*)(outb + (size_t)n * FDIM + q * 8) = o;
    } else {
        float* o = outf + (size_t)n * FDIM + q * 8;
        ((float4*)o)[0] = make_float4(r0, r1, r2, r3);
        ((float4*)o)[1] = make_float4(r4, r5, r6, r7);
    }
}

// ---------------- layer 2 transform: y4 = h2@Wl2, out = h2@Wr2 + b ----------------
__global__ void k_gemm4(const float* __restrict__ h2,
                        const float* __restrict__ Wl,
                        const float* __restrict__ Wr,
                        const float* __restrict__ bias,
                        float* __restrict__ y4,
                        float* __restrict__ outz) {
    int tid = blockIdx.x * blockDim.x + threadIdx.x;
    int n = tid >> 2, c = tid & 3;
    if (n >= NNODES) return;
    const float4* row = (const float4*)(h2 + (size_t)n * FDIM);
    float a = 0, b = 0;
#pragma unroll 8
    for (int k4 = 0; k4 < 32; ++k4) {
        float4 v = row[k4];
        int k = k4 * 4;
        a = fmaf(v.x, Wl[(k + 0) * 4 + c], a); b = fmaf(v.x, Wr[(k + 0) * 4 + c], b);
        a = fmaf(v.y, Wl[(k + 1) * 4 + c], a); b = fmaf(v.y, Wr[(k + 1) * 4 + c], b);
        a = fmaf(v.z, Wl[(k + 2) * 4 + c], a); b = fmaf(v.z, Wr[(k + 2) * 4 + c], b);
        a = fmaf(v.w, Wl[(k + 3) * 4 + c], a); b = fmaf(v.w, Wr[(k + 3) * 4 + c], b);
    }
    y4[(size_t)n * 4 + c] = a;
    outz[(size_t)n * 4 + c] = b + bias[c];
}

// ---------------- layer 2 aggregation (4-wide) + duplicate write ----------------
__global__ void k_agg4(const float* __restrict__ y4,
                       const int* __restrict__ offs,
                       const int* __restrict__ csr,
                       const float* __restrict__ invd,
                       float* __restrict__ out) {
    int tid = blockIdx.x * blockDim.x + threadIdx.x;
    int n = tid >> 2, c = tid & 3;
    if (n >= NNODES) return;
    int beg = offs[n], end = offs[n + 1];
    float acc = 0;
    for (int i = beg; i < end; ++i) acc += y4[(size_t)csr[i] * 4 + c];
    float r = fmaf(acc, invd[n], out[(size_t)n * 4 + c]);
    out[(size_t)n * 4 + c] = r;
    out[(size_t)NNODES * NCLS + (size_t)n * 4 + c] = r;
}

extern "C" void kernel_launch(void* const* d_in, const int* in_sizes, int n_in,
                              void* d_out, int out_size, void* d_ws, size_t ws_size,
                              hipStream_t stream) {
    const float* x   = (const float*)d_in[0];
    const int* ei    = (const int*)d_in[1];
    const float* Wl0 = (const float*)d_in[2];
    const float* bl0 = (const float*)d_in[3];
    const float* Wr0 = (const float*)d_in[4];
    const float* Wl1 = (const float*)d_in[5];
    const float* bl1 = (const float*)d_in[6];
    const float* Wr1 = (const float*)d_in[7];
    const float* Wl2 = (const float*)d_in[8];
    const float* bl2 = (const float*)d_in[9];
    const float* Wr2 = (const float*)d_in[10];

    const int* src = ei;
    const int* dst = ei + NEDGES;

    float* out = (float*)d_out;
    float* h2  = out + 2 * (size_t)NNODES * NCLS;   // [N,128] fp32 lives in d_out

    // workspace layout (256B-aligned offsets), total ~43.2 MB
    char* ws = (char*)d_ws;
    int*   offs = (int*)(ws + 0);              // (N+1) ints
    int*   degc = (int*)(ws + 200192);         // N ints: histogram, then cursor
    float* invd = (float*)(ws + 400384);       // N floats
    int*   bsum = (int*)(ws + 600576);         // 256 ints
    int*   csr  = (int*)(ws + 601600);         // E ints
    u16*   y    = (u16*)(ws + 3801600);        // N*128 bf16 (Wl-transformed msgs)
    u16*   xb   = (u16*)(ws + 16601600);       // N*128 bf16: x cast, then h (aliased)
    u16*   hb   = xb;                          // layer-0 output reuses xb (xb dead by then)
    u16*   zb   = (u16*)(ws + 29401600);       // N*128 bf16 self-term
    float* y4   = (float*)(ws + 42201600);     // N*4 floats
    u16*   Bp0  = (u16*)(ws + 43001600);       // 32768 bf16 packed weights L0
    u16*   Bp1  = (u16*)(ws + 43067136);       // 32768 bf16 packed weights L1

    // ---- graph structure (CSR) ----
    hipMemsetAsync(degc, 0, (size_t)NNODES * sizeof(int), stream);
    k_deg<<<(NEDGES + 255) / 256, 256, 0, stream>>>(dst, degc);
    k_inv<<<SCAN_BLOCKS, 256, 0, stream>>>(degc, invd);
    k_scan1<<<SCAN_BLOCKS, 256, 0, stream>>>(degc, offs, bsum);
    k_scan2<<<1, 256, 0, stream>>>(bsum);
    k_scan3<<<SCAN_BLOCKS, 256, 0, stream>>>(offs, bsum, degc);
    k_fill<<<(NEDGES + 255) / 256, 256, 0, stream>>>(src, dst, degc, csr);

    // ---- precompute: x -> bf16, weights -> packed bf16 fragments ----
    k_cast<<<3125, 256, 0, stream>>>(x, xb);
    k_pack<<<128, 256, 0, stream>>>(Wl0, Wr0, Bp0);
    k_pack<<<128, 256, 0, stream>>>(Wl1, Wr1, Bp1);

    const int mfmaBlocks = (NNODES + 63) / 64;  // 782

    // ---- layer 0: x -> h (relu, bf16) ----
    k_mfma<<<mfmaBlocks, 256, 0, stream>>>(xb, (const uint4*)Bp0, bl0, y, zb);
    k_agg<1, 1><<<NNODES / 16, 256, 0, stream>>>(y, offs, csr, invd, zb, hb, nullptr);

    // ---- layer 1: h -> h2 (fp32, in d_out) ----
    k_mfma<<<mfmaBlocks, 256, 0, stream>>>(hb, (const uint4*)Bp1, bl1, y, zb);
    k_agg<0, 0><<<NNODES / 16, 256, 0, stream>>>(y, offs, csr, invd, zb, nullptr, h2);

    // ---- layer 2: h2 -> out [N,4], duplicated ----
    k_gemm4<<<(NNODES * NCLS + 255) / 256, 256, 0, stream>>>(h2, Wl2, Wr2, bl2, y4, out);
    k_agg4<<<(NNODES * NCLS + 255) / 256, 256, 0, stream>>>(y4, offs, csr, invd, out);
}

// Round 4
// 320.034 us; speedup vs baseline: 14.1823x; 1.1292x over previous
//
#include <hip/hip_runtime.h>
#include <hip/hip_bf16.h>
#include <stdint.h>

#define NNODES 50000
#define NEDGES 800000
#define FDIM   128
#define NCLS   4
#define NB     196        // buckets of 256 nodes: ceil(50000/256)
#define ECAP   6144       // LDS edge-stage capacity per bucket (mean 4082, sigma 64)
#define LPITCH 136        // LDS row pitch in bf16 elements for MFMA A-tile

typedef uint32_t u32;
typedef unsigned short u16;
typedef __bf16 bf16x8 __attribute__((ext_vector_type(8)));
typedef float f32x4 __attribute__((ext_vector_type(4)));

__device__ __forceinline__ u16 f2bf(float f) {
    u32 u = __float_as_uint(f);
    u32 r = u + 0x7fffu + ((u >> 16) & 1u);   // round-to-nearest-even
    return (u16)(r >> 16);
}
__device__ __forceinline__ u32 pack2(float a, float b) {
    return (u32)f2bf(a) | ((u32)f2bf(b) << 16);
}
__device__ __forceinline__ float bflo(u32 p) { return __uint_as_float(p << 16); }
__device__ __forceinline__ float bfhi(u32 p) { return __uint_as_float(p & 0xffff0000u); }

// ---------------- bucketed CSR build ----------------
// pass 1: edge histogram over 196 dst-buckets
__global__ void k_bhist(const int* __restrict__ dst, int* __restrict__ bcnt) {
    __shared__ int h[NB];
    int t = threadIdx.x;
    if (t < NB) h[t] = 0;
    __syncthreads();
    int base = blockIdx.x * 1024;
#pragma unroll
    for (int i = 0; i < 4; ++i) {
        int e = base + i * 256 + t;
        if (e < NEDGES) atomicAdd(&h[dst[e] >> 8], 1);
    }
    __syncthreads();
    if (t < NB) {
        int v = h[t];
        if (v) atomicAdd(&bcnt[t], v);
    }
}

// pass 2: exclusive scan of bucket counts -> boffs, init cursors
__global__ void k_bscan(const int* __restrict__ bcnt, int* __restrict__ boffs,
                        int* __restrict__ bcur) {
    int t = threadIdx.x;
    int v = (t < NB) ? bcnt[t] : 0;
    __shared__ int s[256];
    s[t] = v;
    __syncthreads();
    for (int off = 1; off < 256; off <<= 1) {
        int u = (t >= off) ? s[t - off] : 0;
        __syncthreads();
        s[t] += u;
        __syncthreads();
    }
    if (t < NB) { int ex = s[t] - v; boffs[t] = ex; bcur[t] = ex; }
    if (t == 0) boffs[NB] = NEDGES;
}

// pass 3: partition packed edges (src | dst<<16) into bucket regions
__global__ void k_bscatter(const int* __restrict__ src, const int* __restrict__ dst,
                           int* __restrict__ bcur, u32* __restrict__ ebuf) {
    __shared__ int h[NB];
    __shared__ int base[NB];
    int t = threadIdx.x;
    if (t < NB) h[t] = 0;
    __syncthreads();
    int eb = blockIdx.x * 1024;
    int mb[4];
    u32 pk[4];
#pragma unroll
    for (int i = 0; i < 4; ++i) {
        int e = eb + i * 256 + t;
        if (e < NEDGES) {
            int d = dst[e];
            mb[i] = d >> 8;
            pk[i] = (u32)src[e] | ((u32)d << 16);
            atomicAdd(&h[mb[i]], 1);
        } else mb[i] = -1;
    }
    __syncthreads();
    if (t < NB) {
        int v = h[t];
        base[t] = v ? atomicAdd(&bcur[t], v) : 0;
        h[t] = 0;
    }
    __syncthreads();
#pragma unroll
    for (int i = 0; i < 4; ++i) {
        if (mb[i] >= 0) {
            int r = atomicAdd(&h[mb[i]], 1);
            ebuf[base[mb[i]] + r] = pk[i];
        }
    }
}

// pass 4: per-bucket local CSR finalize (offs, invd, csr), one block per bucket
__global__ void __launch_bounds__(256) k_bfinal(
        const u32* __restrict__ ebuf, const int* __restrict__ boffs,
        int* __restrict__ offs, float* __restrict__ invd, int* __restrict__ csr) {
    __shared__ u32 se[ECAP];
    __shared__ int deg[256];
    __shared__ int s[256];
    int b = blockIdx.x, t = threadIdx.x;
    int nbase = b << 8;
    int ebeg = boffs[b], eend = boffs[b + 1];
    int ecnt = eend - ebeg;
    deg[t] = 0;
    __syncthreads();
    // stage + per-node histogram
    for (int i = t; i < ecnt; i += 256) {
        u32 e = ebuf[ebeg + i];
        if (i < ECAP) se[i] = e;
        atomicAdd(&deg[(e >> 16) - nbase], 1);
    }
    __syncthreads();
    int d = deg[t];
    s[t] = d;
    __syncthreads();
    for (int off = 1; off < 256; off <<= 1) {
        int u = (t >= off) ? s[t - off] : 0;
        __syncthreads();
        s[t] += u;
        __syncthreads();
    }
    int ex = s[t] - d;
    int node = nbase + t;
    if (node < NNODES) {
        offs[node] = ebeg + ex;
        invd[node] = (d > 0) ? (1.0f / (float)d) : 0.0f;
    }
    __syncthreads();
    deg[t] = ex;   // reuse as local cursor
    __syncthreads();
    // place src ids: writes confined to this bucket's contiguous csr region
    for (int i = t; i < ecnt; i += 256) {
        u32 e = (i < ECAP) ? se[i] : ebuf[ebeg + i];
        int dl = (int)(e >> 16) - nbase;
        int r = atomicAdd(&deg[dl], 1);
        csr[ebeg + r] = (int)(e & 0xffffu);
    }
    if (b == 0 && t == 0) offs[NNODES] = NEDGES;
}

// ---------------- fp32 -> bf16 cast (x input), 8 elems/thread ----------------
__global__ void k_cast(const float* __restrict__ in, u16* __restrict__ out) {
    int i = blockIdx.x * 256 + threadIdx.x;    // 800000 threads total
    const float4* p = (const float4*)in + (size_t)i * 2;
    float4 a = p[0], b = p[1];
    uint4 r;
    r.x = pack2(a.x, a.y); r.y = pack2(a.z, a.w);
    r.z = pack2(b.x, b.y); r.w = pack2(b.z, b.w);
    ((uint4*)out)[i] = r;
}

// ---------------- weight pack: [Wl|Wr] fp32 -> bf16 MFMA B-fragment layout ---
// Bp flat layout: [nt(16)][ks(4)][lane(64)][j(8)], value = Wcat[k][col]
// col = nt*16 + (lane&15), k = ks*32 + (lane>>4)*8 + j
__global__ void k_pack(const float* __restrict__ Wl, const float* __restrict__ Wr,
                       u16* __restrict__ Bp) {
    int tid = blockIdx.x * 256 + threadIdx.x;  // 0..32767
    int j    = tid & 7;
    int lane = (tid >> 3) & 63;
    int ks   = (tid >> 9) & 3;
    int nt   = tid >> 11;
    int col  = nt * 16 + (lane & 15);
    int k    = ks * 32 + (lane >> 4) * 8 + j;
    float v = (col < FDIM) ? Wl[k * FDIM + col] : Wr[k * FDIM + (col - FDIM)];
    Bp[tid] = f2bf(v);
}

// ---------------- MFMA dual GEMM: y = in@Wl (bf16), zb = in@Wr + b (bf16) ----
__global__ void __launch_bounds__(256) k_mfma(
        const u16* __restrict__ inb,      // [N][128] bf16
        const uint4* __restrict__ Bp,     // packed fragments
        const float* __restrict__ bias,   // [128]
        u16* __restrict__ y,              // [N][128] bf16
        u16* __restrict__ zb) {           // [N][128] bf16
    __shared__ u16 sA[64 * LPITCH];
    int t = threadIdx.x;
    int blk = blockIdx.x;

    {
        int row = t >> 2;
        int g4  = (t & 3) * 4;
        int r = blk * 64 + row;
        if (r >= NNODES) r = NNODES - 1;
        const uint4* gsrc = (const uint4*)(inb + (size_t)r * FDIM);
        uint4* ldst = (uint4*)(sA + row * LPITCH);
#pragma unroll
        for (int i = 0; i < 4; ++i) ldst[g4 + i] = gsrc[g4 + i];
    }
    __syncthreads();

    int wave = t >> 6;
    int lane = t & 63;
    int m    = lane & 15;
    int quad = lane >> 4;

    bf16x8 a[4][4];
#pragma unroll
    for (int mt = 0; mt < 4; ++mt)
#pragma unroll
        for (int ks = 0; ks < 4; ++ks) {
            const uint4* ap = (const uint4*)(sA + (mt * 16 + m) * LPITCH + ks * 32 + quad * 8);
            a[mt][ks] = __builtin_bit_cast(bf16x8, *ap);
        }

    f32x4 acc[4][4];
#pragma unroll
    for (int mt = 0; mt < 4; ++mt)
#pragma unroll
        for (int nt = 0; nt < 4; ++nt) acc[mt][nt] = (f32x4){0.f, 0.f, 0.f, 0.f};

#pragma unroll
    for (int ks = 0; ks < 4; ++ks) {
#pragma unroll
        for (int nt = 0; nt < 4; ++nt) {
            int ntg = wave * 4 + nt;
            bf16x8 b = __builtin_bit_cast(bf16x8, Bp[(ntg * 4 + ks) * 64 + lane]);
#pragma unroll
            for (int mt = 0; mt < 4; ++mt)
                acc[mt][nt] = __builtin_amdgcn_mfma_f32_16x16x32_bf16(
                    a[mt][ks], b, acc[mt][nt], 0, 0, 0);
        }
    }

#pragma unroll
    for (int nt = 0; nt < 4; ++nt) {
        int ntg = wave * 4 + nt;
        int col = ntg * 16 + m;
#pragma unroll
        for (int mt = 0; mt < 4; ++mt) {
            int grow = blk * 64 + mt * 16 + quad * 4;
#pragma unroll
            for (int r = 0; r < 4; ++r) {
                int gr = grow + r;
                if (gr < NNODES) {
                    if (col < FDIM) {
                        y[(size_t)gr * FDIM + col] = f2bf(acc[mt][nt][r]);
                    } else {
                        float bv = bias[col - FDIM];
                        zb[(size_t)gr * FDIM + (col - FDIM)] = f2bf(acc[mt][nt][r] + bv);
                    }
                }
            }
        }
    }
}

// ---------------- gather aggregation + epilogue (128-wide) ----------------
template <int RELU, int OUTBF>
__global__ void k_agg(const u16* __restrict__ y,
                      const int* __restrict__ offs,
                      const int* __restrict__ csr,
                      const float* __restrict__ invd,
                      const u16* __restrict__ zb,
                      u16* __restrict__ outb,
                      float* __restrict__ outf) {
    int t = threadIdx.x;
    int nl = t >> 4, q = t & 15;
    int n = blockIdx.x * 16 + nl;
    int beg = offs[n], end = offs[n + 1];
    float a0 = 0, a1 = 0, a2 = 0, a3 = 0, a4 = 0, a5 = 0, a6 = 0, a7 = 0;
    const u16* yq = y + (size_t)q * 8;
    for (int i = beg; i < end; ++i) {
        int s = csr[i];
        uint4 v = *(const uint4*)(yq + (size_t)s * FDIM);
        a0 += bflo(v.x); a1 += bfhi(v.x);
        a2 += bflo(v.y); a3 += bfhi(v.y);
        a4 += bflo(v.z); a5 += bfhi(v.z);
        a6 += bflo(v.w); a7 += bfhi(v.w);
    }
    float iv = invd[n];
    uint4 zv = *(const uint4*)(zb + (size_t)n * FDIM + q * 8);
    float r0 = fmaf(a0, iv, bflo(zv.x)), r1 = fmaf(a1, iv, bfhi(zv.x));
    float r2 = fmaf(a2, iv, bflo(zv.y)), r3 = fmaf(a3, iv, bfhi(zv.y));
    float r4 = fmaf(a4, iv, bflo(zv.z)), r5 = fmaf(a5, iv, bfhi(zv.z));
    float r6 = fmaf(a6, iv, bflo(zv.w)), r7 = fmaf(a7, iv, bfhi(zv.w));
    if (RELU) {
        r0 = fmaxf(r0, 0.f); r1 = fmaxf(r1, 0.f); r2 = fmaxf(r2, 0.f); r3 = fmaxf(r3, 0.f);
        r4 = fmaxf(r4, 0.f); r5 = fmaxf(r5, 0.f); r6 = fmaxf(r6, 0.f); r7 = fmaxf(r7, 0.f);
    }
    if (OUTBF) {
        uint4 o;
        o.x = pack2(r0, r1); o.y = pack2(r2, r3);
        o.z = pack2(r4, r5); o.w = pack2(r6, r7);
        *(uint4*)(outb + (size_t)n * FDIM + q * 8) = o;
    } else {
        float* o = outf + (size_t)n * FDIM + q * 8;
        ((float4*)o)[0] = make_float4(r0, r1, r2, r3);
        ((float4*)o)[1] = make_float4(r4, r5, r6, r7);
    }
}

// ---------------- layer 2 transform: y4 = h2@Wl2, out = h2@Wr2 + b ----------------
__global__ void k_gemm4(const float* __restrict__ h2,
                        const float* __restrict__ Wl,
                        const float* __restrict__ Wr,
                        const float* __restrict__ bias,
                        float* __restrict__ y4,
                        float* __restrict__ outz) {
    int tid = blockIdx.x * blockDim.x + threadIdx.x;
    int n = tid >> 2, c = tid & 3;
    if (n >= NNODES) return;
    const float4* row = (const float4*)(h2 + (size_t)n * FDIM);
    float a = 0, b = 0;
#pragma unroll 8
    for (int k4 = 0; k4 < 32; ++k4) {
        float4 v = row[k4];
        int k = k4 * 4;
        a = fmaf(v.x, Wl[(k + 0) * 4 + c], a); b = fmaf(v.x, Wr[(k + 0) * 4 + c], b);
        a = fmaf(v.y, Wl[(k + 1) * 4 + c], a); b = fmaf(v.y, Wr[(k + 1) * 4 + c], b);
        a = fmaf(v.z, Wl[(k + 2) * 4 + c], a); b = fmaf(v.z, Wr[(k + 2) * 4 + c], b);
        a = fmaf(v.w, Wl[(k + 3) * 4 + c], a); b = fmaf(v.w, Wr[(k + 3) * 4 + c], b);
    }
    y4[(size_t)n * 4 + c] = a;
    outz[(size_t)n * 4 + c] = b + bias[c];
}

// ---------------- layer 2 aggregation (4-wide) + duplicate write ----------------
__global__ void k_agg4(const float* __restrict__ y4,
                       const int* __restrict__ offs,
                       const int* __restrict__ csr,
                       const float* __restrict__ invd,
                       float* __restrict__ out) {
    int tid = blockIdx.x * blockDim.x + threadIdx.x;
    int n = tid >> 2, c = tid & 3;
    if (n >= NNODES) return;
    int beg = offs[n], end = offs[n + 1];
    float acc = 0;
    for (int i = beg; i < end; ++i) acc += y4[(size_t)csr[i] * 4 + c];
    float r = fmaf(acc, invd[n], out[(size_t)n * 4 + c]);
    out[(size_t)n * 4 + c] = r;
    out[(size_t)NNODES * NCLS + (size_t)n * 4 + c] = r;
}

extern "C" void kernel_launch(void* const* d_in, const int* in_sizes, int n_in,
                              void* d_out, int out_size, void* d_ws, size_t ws_size,
                              hipStream_t stream) {
    const float* x   = (const float*)d_in[0];
    const int* ei    = (const int*)d_in[1];
    const float* Wl0 = (const float*)d_in[2];
    const float* bl0 = (const float*)d_in[3];
    const float* Wr0 = (const float*)d_in[4];
    const float* Wl1 = (const float*)d_in[5];
    const float* bl1 = (const float*)d_in[6];
    const float* Wr1 = (const float*)d_in[7];
    const float* Wl2 = (const float*)d_in[8];
    const float* bl2 = (const float*)d_in[9];
    const float* Wr2 = (const float*)d_in[10];

    const int* src = ei;
    const int* dst = ei + NEDGES;

    float* out = (float*)d_out;
    float* h2  = out + 2 * (size_t)NNODES * NCLS;   // [N,128] fp32 lives in d_out

    // workspace layout (256B-aligned), total ~42.9 MB
    char* ws = (char*)d_ws;
    int*   offs = (int*)(ws + 0);              // (N+1) ints
    float* invd = (float*)(ws + 200192);       // N floats
    int*   bcnt = (int*)(ws + 400384);         // NB ints
    int*   boffs= (int*)(ws + 401408);         // NB+1 ints
    int*   bcur = (int*)(ws + 402432);         // NB ints
    int*   csr  = (int*)(ws + 403456);         // E ints
    u16*   y    = (u16*)(ws + 3603456);        // N*128 bf16 (Wl-transformed msgs)
    u16*   xb   = (u16*)(ws + 16403456);       // N*128 bf16: x cast, then h (aliased)
    u16*   hb   = xb;
    u16*   zb   = (u16*)(ws + 29203456);       // N*128 bf16 self-term
    u32*   ebuf = (u32*)zb;                    // E u32, dead before zb is written
    float* y4   = (float*)(ws + 42003456);     // N*4 floats
    u16*   Bp0  = (u16*)(ws + 42803456);       // 32768 bf16 packed weights L0
    u16*   Bp1  = (u16*)(ws + 42868992);       // 32768 bf16 packed weights L1

    // ---- graph structure: bucketed CSR build ----
    hipMemsetAsync(bcnt, 0, NB * sizeof(int), stream);
    k_bhist<<<782, 256, 0, stream>>>(dst, bcnt);
    k_bscan<<<1, 256, 0, stream>>>(bcnt, boffs, bcur);
    k_bscatter<<<782, 256, 0, stream>>>(src, dst, bcur, ebuf);
    k_bfinal<<<NB, 256, 0, stream>>>(ebuf, boffs, offs, invd, csr);

    // ---- precompute: x -> bf16, weights -> packed bf16 fragments ----
    k_cast<<<3125, 256, 0, stream>>>(x, xb);
    k_pack<<<128, 256, 0, stream>>>(Wl0, Wr0, Bp0);
    k_pack<<<128, 256, 0, stream>>>(Wl1, Wr1, Bp1);

    const int mfmaBlocks = (NNODES + 63) / 64;  // 782

    // ---- layer 0: x -> h (relu, bf16) ----
    k_mfma<<<mfmaBlocks, 256, 0, stream>>>(xb, (const uint4*)Bp0, bl0, y, zb);
    k_agg<1, 1><<<NNODES / 16, 256, 0, stream>>>(y, offs, csr, invd, zb, hb, nullptr);

    // ---- layer 1: h -> h2 (fp32, in d_out) ----
    k_mfma<<<mfmaBlocks, 256, 0, stream>>>(hb, (const uint4*)Bp1, bl1, y, zb);
    k_agg<0, 0><<<NNODES / 16, 256, 0, stream>>>(y, offs, csr, invd, zb, nullptr, h2);

    // ---- layer 2: h2 -> out [N,4], duplicated ----
    k_gemm4<<<(NNODES * NCLS + 255) / 256, 256, 0, stream>>>(h2, Wl2, Wr2, bl2, y4, out);
    k_agg4<<<(NNODES * NCLS + 255) / 256, 256, 0, stream>>>(y4, offs, csr, invd, out);
}

// Round 5
// 315.751 us; speedup vs baseline: 14.3747x; 1.0136x over previous
//
#include <hip/hip_runtime.h>
#include <hip/hip_bf16.h>
#include <stdint.h>

#define NNODES 50000
#define NEDGES 800000
#define FDIM   128
#define NCLS   4
#define NB     196        // buckets of 256 nodes: ceil(50000/256)
#define ECAP   6144       // LDS edge-stage capacity per bucket (mean 4082, sigma 64)
#define LPITCH 136        // LDS row pitch in bf16 elements for MFMA A-tile
#define NPH    8          // source phases (src>>13); phase working set ~2.1 MB of y

typedef uint32_t u32;
typedef unsigned short u16;
typedef __bf16 bf16x8 __attribute__((ext_vector_type(8)));
typedef float f32x4 __attribute__((ext_vector_type(4)));

__device__ __forceinline__ u16 f2bf(float f) {
    u32 u = __float_as_uint(f);
    u32 r = u + 0x7fffu + ((u >> 16) & 1u);   // round-to-nearest-even
    return (u16)(r >> 16);
}
__device__ __forceinline__ u32 pack2(float a, float b) {
    return (u32)f2bf(a) | ((u32)f2bf(b) << 16);
}
__device__ __forceinline__ float bflo(u32 p) { return __uint_as_float(p << 16); }
__device__ __forceinline__ float bfhi(u32 p) { return __uint_as_float(p & 0xffff0000u); }

// ---------------- bucketed CSR build ----------------
// pass 1: edge histogram over 196 dst-buckets
__global__ void k_bhist(const int* __restrict__ dst, int* __restrict__ bcnt) {
    __shared__ int h[NB];
    int t = threadIdx.x;
    if (t < NB) h[t] = 0;
    __syncthreads();
    int base = blockIdx.x * 1024;
#pragma unroll
    for (int i = 0; i < 4; ++i) {
        int e = base + i * 256 + t;
        if (e < NEDGES) atomicAdd(&h[dst[e] >> 8], 1);
    }
    __syncthreads();
    if (t < NB) {
        int v = h[t];
        if (v) atomicAdd(&bcnt[t], v);
    }
}

// pass 2: exclusive scan of bucket counts -> boffs, init cursors
__global__ void k_bscan(const int* __restrict__ bcnt, int* __restrict__ boffs,
                        int* __restrict__ bcur) {
    int t = threadIdx.x;
    int v = (t < NB) ? bcnt[t] : 0;
    __shared__ int s[256];
    s[t] = v;
    __syncthreads();
    for (int off = 1; off < 256; off <<= 1) {
        int u = (t >= off) ? s[t - off] : 0;
        __syncthreads();
        s[t] += u;
        __syncthreads();
    }
    if (t < NB) { int ex = s[t] - v; boffs[t] = ex; bcur[t] = ex; }
    if (t == 0) boffs[NB] = NEDGES;
}

// pass 3: partition packed edges (src | dst<<16) into bucket regions
__global__ void k_bscatter(const int* __restrict__ src, const int* __restrict__ dst,
                           int* __restrict__ bcur, u32* __restrict__ ebuf) {
    __shared__ int h[NB];
    __shared__ int base[NB];
    int t = threadIdx.x;
    if (t < NB) h[t] = 0;
    __syncthreads();
    int eb = blockIdx.x * 1024;
    int mb[4];
    u32 pk[4];
#pragma unroll
    for (int i = 0; i < 4; ++i) {
        int e = eb + i * 256 + t;
        if (e < NEDGES) {
            int d = dst[e];
            mb[i] = d >> 8;
            pk[i] = (u32)src[e] | ((u32)d << 16);
            atomicAdd(&h[mb[i]], 1);
        } else mb[i] = -1;
    }
    __syncthreads();
    if (t < NB) {
        int v = h[t];
        base[t] = v ? atomicAdd(&bcur[t], v) : 0;
        h[t] = 0;
    }
    __syncthreads();
#pragma unroll
    for (int i = 0; i < 4; ++i) {
        if (mb[i] >= 0) {
            int r = atomicAdd(&h[mb[i]], 1);
            ebuf[base[mb[i]] + r] = pk[i];
        }
    }
}

// pass 4: per-bucket CSR finalize with per-node PHASE-SORTED edge lists.
// Each node's csr slice is ordered by src>>13 so the aggregation kernel's
// sequential walk visits sources in ascending-phase order (L2-resident window).
__global__ void __launch_bounds__(256) k_bfinal(
        const u32* __restrict__ ebuf, const int* __restrict__ boffs,
        int* __restrict__ offs, float* __restrict__ invd, int* __restrict__ csr) {
    __shared__ u32 se[ECAP];
    __shared__ int deg8[256 * NPH];   // [node][phase]
    __shared__ int s[256];
    int b = blockIdx.x, t = threadIdx.x;
    int nbase = b << 8;
    int ebeg = boffs[b], eend = boffs[b + 1];
    int ecnt = eend - ebeg;
#pragma unroll
    for (int j = 0; j < NPH; ++j) deg8[t * NPH + j] = 0;
    __syncthreads();
    // stage + per-node-per-phase histogram
    for (int i = t; i < ecnt; i += 256) {
        u32 e = ebuf[ebeg + i];
        if (i < ECAP) se[i] = e;
        int dl = (int)(e >> 16) - nbase;
        int ph = (int)(e & 0xffffu) >> 13;
        atomicAdd(&deg8[dl * NPH + ph], 1);
    }
    __syncthreads();
    // local prefix over this node's phases
    int pre[NPH];
    int run = 0;
#pragma unroll
    for (int j = 0; j < NPH; ++j) { pre[j] = run; run += deg8[t * NPH + j]; }
    int d = run;
    s[t] = d;
    __syncthreads();
    for (int off = 1; off < 256; off <<= 1) {
        int u = (t >= off) ? s[t - off] : 0;
        __syncthreads();
        s[t] += u;
        __syncthreads();
    }
    int ex = s[t] - d;   // node-exclusive within bucket
    int node = nbase + t;
    if (node < NNODES) {
        offs[node] = ebeg + ex;
        invd[node] = (d > 0) ? (1.0f / (float)d) : 0.0f;
    }
    __syncthreads();
#pragma unroll
    for (int j = 0; j < NPH; ++j) deg8[t * NPH + j] = ex + pre[j];   // cursors
    __syncthreads();
    // place src ids grouped by phase within each node's slice
    for (int i = t; i < ecnt; i += 256) {
        u32 e = (i < ECAP) ? se[i] : ebuf[ebeg + i];
        int dl = (int)(e >> 16) - nbase;
        int sv = (int)(e & 0xffffu);
        int r = atomicAdd(&deg8[dl * NPH + (sv >> 13)], 1);
        csr[ebeg + r] = sv;
    }
    if (b == 0 && t == 0) offs[NNODES] = NEDGES;
}

// ---------------- weight pack: [Wl|Wr] fp32 -> bf16 MFMA B-fragment layout ---
// Bp flat layout: [nt(16)][ks(4)][lane(64)][j(8)], value = Wcat[k][col]
// col = nt*16 + (lane&15), k = ks*32 + (lane>>4)*8 + j
__global__ void k_pack(const float* __restrict__ Wl, const float* __restrict__ Wr,
                       u16* __restrict__ Bp) {
    int tid = blockIdx.x * 256 + threadIdx.x;  // 0..32767
    int j    = tid & 7;
    int lane = (tid >> 3) & 63;
    int ks   = (tid >> 9) & 3;
    int nt   = tid >> 11;
    int col  = nt * 16 + (lane & 15);
    int k    = ks * 32 + (lane >> 4) * 8 + j;
    float v = (col < FDIM) ? Wl[k * FDIM + col] : Wr[k * FDIM + (col - FDIM)];
    Bp[tid] = f2bf(v);
}

// ---------------- MFMA dual GEMM: y = in@Wl (bf16), zb = in@Wr + b (bf16) ----
// INF32=1: input is fp32 (layer 0, x) — cast fused into LDS staging.
template <int INF32>
__global__ void __launch_bounds__(256) k_mfma(
        const void* __restrict__ in,      // [N][128] bf16 or fp32
        const uint4* __restrict__ Bp,     // packed fragments
        const float* __restrict__ bias,   // [128]
        u16* __restrict__ y,              // [N][128] bf16
        u16* __restrict__ zb) {           // [N][128] bf16
    __shared__ u16 sA[64 * LPITCH];
    int t = threadIdx.x;
    int blk = blockIdx.x;

    {
        int row = t >> 2;
        int q   = t & 3;
        int r = blk * 64 + row;
        if (r >= NNODES) r = NNODES - 1;
        if (INF32) {
            const float4* gs = (const float4*)((const float*)in + (size_t)r * FDIM) + q * 8;
            uint4* ld = (uint4*)(sA + row * LPITCH + q * 32);
#pragma unroll
            for (int i = 0; i < 4; ++i) {
                float4 a = gs[2 * i], b = gs[2 * i + 1];
                uint4 v;
                v.x = pack2(a.x, a.y); v.y = pack2(a.z, a.w);
                v.z = pack2(b.x, b.y); v.w = pack2(b.z, b.w);
                ld[i] = v;
            }
        } else {
            const uint4* gsrc = (const uint4*)((const u16*)in + (size_t)r * FDIM);
            uint4* ldst = (uint4*)(sA + row * LPITCH);
#pragma unroll
            for (int i = 0; i < 4; ++i) ldst[q * 4 + i] = gsrc[q * 4 + i];
        }
    }
    __syncthreads();

    int wave = t >> 6;
    int lane = t & 63;
    int m    = lane & 15;
    int quad = lane >> 4;

    bf16x8 a[4][4];
#pragma unroll
    for (int mt = 0; mt < 4; ++mt)
#pragma unroll
        for (int ks = 0; ks < 4; ++ks) {
            const uint4* ap = (const uint4*)(sA + (mt * 16 + m) * LPITCH + ks * 32 + quad * 8);
            a[mt][ks] = __builtin_bit_cast(bf16x8, *ap);
        }

    f32x4 acc[4][4];
#pragma unroll
    for (int mt = 0; mt < 4; ++mt)
#pragma unroll
        for (int nt = 0; nt < 4; ++nt) acc[mt][nt] = (f32x4){0.f, 0.f, 0.f, 0.f};

#pragma unroll
    for (int ks = 0; ks < 4; ++ks) {
#pragma unroll
        for (int nt = 0; nt < 4; ++nt) {
            int ntg = wave * 4 + nt;
            bf16x8 b = __builtin_bit_cast(bf16x8, Bp[(ntg * 4 + ks) * 64 + lane]);
#pragma unroll
            for (int mt = 0; mt < 4; ++mt)
                acc[mt][nt] = __builtin_amdgcn_mfma_f32_16x16x32_bf16(
                    a[mt][ks], b, acc[mt][nt], 0, 0, 0);
        }
    }

#pragma unroll
    for (int nt = 0; nt < 4; ++nt) {
        int ntg = wave * 4 + nt;
        int col = ntg * 16 + m;
#pragma unroll
        for (int mt = 0; mt < 4; ++mt) {
            int grow = blk * 64 + mt * 16 + quad * 4;
#pragma unroll
            for (int r = 0; r < 4; ++r) {
                int gr = grow + r;
                if (gr < NNODES) {
                    if (col < FDIM) {
                        y[(size_t)gr * FDIM + col] = f2bf(acc[mt][nt][r]);
                    } else {
                        float bv = bias[col - FDIM];
                        zb[(size_t)gr * FDIM + (col - FDIM)] = f2bf(acc[mt][nt][r] + bv);
                    }
                }
            }
        }
    }
}

// ---------------- gather aggregation + epilogue (128-wide) ----------------
// 16 lanes per node; csr entries are phase-sorted so the walk has L2 locality.
template <int RELU, int OUTBF>
__global__ void k_agg(const u16* __restrict__ y,
                      const int* __restrict__ offs,
                      const int* __restrict__ csr,
                      const float* __restrict__ invd,
                      const u16* __restrict__ zb,
                      u16* __restrict__ outb,
                      float* __restrict__ outf) {
    int t = threadIdx.x;
    int nl = t >> 4, q = t & 15;
    int n = blockIdx.x * 16 + nl;
    int beg = offs[n], end = offs[n + 1];
    float a0 = 0, a1 = 0, a2 = 0, a3 = 0, a4 = 0, a5 = 0, a6 = 0, a7 = 0;
    const u16* yq = y + (size_t)q * 8;
    for (int i = beg; i < end; ++i) {
        int s = csr[i];
        uint4 v = *(const uint4*)(yq + (size_t)s * FDIM);
        a0 += bflo(v.x); a1 += bfhi(v.x);
        a2 += bflo(v.y); a3 += bfhi(v.y);
        a4 += bflo(v.z); a5 += bfhi(v.z);
        a6 += bflo(v.w); a7 += bfhi(v.w);
    }
    float iv = invd[n];
    uint4 zv = *(const uint4*)(zb + (size_t)n * FDIM + q * 8);
    float r0 = fmaf(a0, iv, bflo(zv.x)), r1 = fmaf(a1, iv, bfhi(zv.x));
    float r2 = fmaf(a2, iv, bflo(zv.y)), r3 = fmaf(a3, iv, bfhi(zv.y));
    float r4 = fmaf(a4, iv, bflo(zv.z)), r5 = fmaf(a5, iv, bfhi(zv.z));
    float r6 = fmaf(a6, iv, bflo(zv.w)), r7 = fmaf(a7, iv, bfhi(zv.w));
    if (RELU) {
        r0 = fmaxf(r0, 0.f); r1 = fmaxf(r1, 0.f); r2 = fmaxf(r2, 0.f); r3 = fmaxf(r3, 0.f);
        r4 = fmaxf(r4, 0.f); r5 = fmaxf(r5, 0.f); r6 = fmaxf(r6, 0.f); r7 = fmaxf(r7, 0.f);
    }
    if (OUTBF) {
        uint4 o;
        o.x = pack2(r0, r1); o.y = pack2(r2, r3);
        o.z = pack2(r4, r5); o.w = pack2(r6, r7);
        *(uint4*)(outb + (size_t)n * FDIM + q * 8) = o;
    } else {
        float* o = outf + (size_t)n * FDIM + q * 8;
        ((float4*)o)[0] = make_float4(r0, r1, r2, r3);
        ((float4*)o)[1] = make_float4(r4, r5, r6, r7);
    }
}

// ---------------- layer 2 transform: y4 = h2@Wl2, out = h2@Wr2 + b ----------------
__global__ void k_gemm4(const float* __restrict__ h2,
                        const float* __restrict__ Wl,
                        const float* __restrict__ Wr,
                        const float* __restrict__ bias,
                        float* __restrict__ y4,
                        float* __restrict__ outz) {
    int tid = blockIdx.x * blockDim.x + threadIdx.x;
    int n = tid >> 2, c = tid & 3;
    if (n >= NNODES) return;
    const float4* row = (const float4*)(h2 + (size_t)n * FDIM);
    float a = 0, b = 0;
#pragma unroll 8
    for (int k4 = 0; k4 < 32; ++k4) {
        float4 v = row[k4];
        int k = k4 * 4;
        a = fmaf(v.x, Wl[(k + 0) * 4 + c], a); b = fmaf(v.x, Wr[(k + 0) * 4 + c], b);
        a = fmaf(v.y, Wl[(k + 1) * 4 + c], a); b = fmaf(v.y, Wr[(k + 1) * 4 + c], b);
        a = fmaf(v.z, Wl[(k + 2) * 4 + c], a); b = fmaf(v.z, Wr[(k + 2) * 4 + c], b);
        a = fmaf(v.w, Wl[(k + 3) * 4 + c], a); b = fmaf(v.w, Wr[(k + 3) * 4 + c], b);
    }
    y4[(size_t)n * 4 + c] = a;
    outz[(size_t)n * 4 + c] = b + bias[c];
}

// ---------------- layer 2 aggregation (4-wide) + duplicate write ----------------
__global__ void k_agg4(const float* __restrict__ y4,
                       const int* __restrict__ offs,
                       const int* __restrict__ csr,
                       const float* __restrict__ invd,
                       float* __restrict__ out) {
    int tid = blockIdx.x * blockDim.x + threadIdx.x;
    int n = tid >> 2, c = tid & 3;
    if (n >= NNODES) return;
    int beg = offs[n], end = offs[n + 1];
    float acc = 0;
    for (int i = beg; i < end; ++i) acc += y4[(size_t)csr[i] * 4 + c];
    float r = fmaf(acc, invd[n], out[(size_t)n * 4 + c]);
    out[(size_t)n * 4 + c] = r;
    out[(size_t)NNODES * NCLS + (size_t)n * 4 + c] = r;
}

extern "C" void kernel_launch(void* const* d_in, const int* in_sizes, int n_in,
                              void* d_out, int out_size, void* d_ws, size_t ws_size,
                              hipStream_t stream) {
    const float* x   = (const float*)d_in[0];
    const int* ei    = (const int*)d_in[1];
    const float* Wl0 = (const float*)d_in[2];
    const float* bl0 = (const float*)d_in[3];
    const float* Wr0 = (const float*)d_in[4];
    const float* Wl1 = (const float*)d_in[5];
    const float* bl1 = (const float*)d_in[6];
    const float* Wr1 = (const float*)d_in[7];
    const float* Wl2 = (const float*)d_in[8];
    const float* bl2 = (const float*)d_in[9];
    const float* Wr2 = (const float*)d_in[10];

    const int* src = ei;
    const int* dst = ei + NEDGES;

    float* out = (float*)d_out;
    float* h2  = out + 2 * (size_t)NNODES * NCLS;   // [N,128] fp32 lives in d_out

    // workspace layout (256B-aligned), total ~42.9 MB
    char* ws = (char*)d_ws;
    int*   offs = (int*)(ws + 0);              // (N+1) ints
    float* invd = (float*)(ws + 200192);       // N floats
    int*   bcnt = (int*)(ws + 400384);         // NB ints
    int*   boffs= (int*)(ws + 401408);         // NB+1 ints
    int*   bcur = (int*)(ws + 402432);         // NB ints
    int*   csr  = (int*)(ws + 403456);         // E ints
    u16*   y    = (u16*)(ws + 3603456);        // N*128 bf16 (Wl-transformed msgs)
    u16*   hb   = (u16*)(ws + 16403456);       // N*128 bf16 layer-0 output
    u16*   zb   = (u16*)(ws + 29203456);       // N*128 bf16 self-term
    u32*   ebuf = (u32*)zb;                    // E u32, dead before zb is written
    float* y4   = (float*)(ws + 42003456);     // N*4 floats
    u16*   Bp0  = (u16*)(ws + 42803456);       // 32768 bf16 packed weights L0
    u16*   Bp1  = (u16*)(ws + 42868992);       // 32768 bf16 packed weights L1

    // ---- graph structure: bucketed CSR build (phase-sorted adjacency) ----
    hipMemsetAsync(bcnt, 0, NB * sizeof(int), stream);
    k_bhist<<<782, 256, 0, stream>>>(dst, bcnt);
    k_bscan<<<1, 256, 0, stream>>>(bcnt, boffs, bcur);
    k_bscatter<<<782, 256, 0, stream>>>(src, dst, bcur, ebuf);
    k_bfinal<<<NB, 256, 0, stream>>>(ebuf, boffs, offs, invd, csr);

    // ---- precompute: weights -> packed bf16 fragments ----
    k_pack<<<128, 256, 0, stream>>>(Wl0, Wr0, Bp0);
    k_pack<<<128, 256, 0, stream>>>(Wl1, Wr1, Bp1);

    const int mfmaBlocks = (NNODES + 63) / 64;  // 782

    // ---- layer 0: x (fp32) -> h (relu, bf16); cast fused into staging ----
    k_mfma<1><<<mfmaBlocks, 256, 0, stream>>>(x, (const uint4*)Bp0, bl0, y, zb);
    k_agg<1, 1><<<NNODES / 16, 256, 0, stream>>>(y, offs, csr, invd, zb, hb, nullptr);

    // ---- layer 1: h -> h2 (fp32, in d_out) ----
    k_mfma<0><<<mfmaBlocks, 256, 0, stream>>>(hb, (const uint4*)Bp1, bl1, y, zb);
    k_agg<0, 0><<<NNODES / 16, 256, 0, stream>>>(y, offs, csr, invd, zb, nullptr, h2);

    // ---- layer 2: h2 -> out [N,4], duplicated ----
    k_gemm4<<<(NNODES * NCLS + 255) / 256, 256, 0, stream>>>(h2, Wl2, Wr2, bl2, y4, out);
    k_agg4<<<(NNODES * NCLS + 255) / 256, 256, 0, stream>>>(y4, offs, csr, invd, out);
}

// Round 6
// 284.570 us; speedup vs baseline: 15.9497x; 1.1096x over previous
//
#include <hip/hip_runtime.h>
#include <hip/hip_bf16.h>
#include <stdint.h>

#define NNODES 50000
#define NEDGES 800000
#define FDIM   128
#define NCLS   4
#define NB     196        // buckets of 256 nodes: ceil(50000/256)
#define ECAP   6144       // LDS edge-stage capacity per bucket (mean 4082, sigma 64)
#define LPITCH 136        // LDS row pitch in u16 (272B) for A-tile AND epilogue stage
#define NPH    8          // source phases (src>>13); phase working set ~2.1 MB of y

typedef uint32_t u32;
typedef unsigned short u16;
typedef __bf16 bf16x8 __attribute__((ext_vector_type(8)));
typedef float f32x4 __attribute__((ext_vector_type(4)));

__device__ __forceinline__ u16 f2bf(float f) {
    u32 u = __float_as_uint(f);
    u32 r = u + 0x7fffu + ((u >> 16) & 1u);   // round-to-nearest-even
    return (u16)(r >> 16);
}
__device__ __forceinline__ u32 pack2(float a, float b) {
    return (u32)f2bf(a) | ((u32)f2bf(b) << 16);
}
__device__ __forceinline__ float bflo(u32 p) { return __uint_as_float(p << 16); }
__device__ __forceinline__ float bfhi(u32 p) { return __uint_as_float(p & 0xffff0000u); }

// ---------------- bucketed CSR build ----------------
__global__ void k_bhist(const int* __restrict__ dst, int* __restrict__ bcnt) {
    __shared__ int h[NB];
    int t = threadIdx.x;
    if (t < NB) h[t] = 0;
    __syncthreads();
    int base = blockIdx.x * 1024;
#pragma unroll
    for (int i = 0; i < 4; ++i) {
        int e = base + i * 256 + t;
        if (e < NEDGES) atomicAdd(&h[dst[e] >> 8], 1);
    }
    __syncthreads();
    if (t < NB) {
        int v = h[t];
        if (v) atomicAdd(&bcnt[t], v);
    }
}

__global__ void k_bscan(const int* __restrict__ bcnt, int* __restrict__ boffs,
                        int* __restrict__ bcur) {
    int t = threadIdx.x;
    int v = (t < NB) ? bcnt[t] : 0;
    __shared__ int s[256];
    s[t] = v;
    __syncthreads();
    for (int off = 1; off < 256; off <<= 1) {
        int u = (t >= off) ? s[t - off] : 0;
        __syncthreads();
        s[t] += u;
        __syncthreads();
    }
    if (t < NB) { int ex = s[t] - v; boffs[t] = ex; bcur[t] = ex; }
    if (t == 0) boffs[NB] = NEDGES;
}

__global__ void k_bscatter(const int* __restrict__ src, const int* __restrict__ dst,
                           int* __restrict__ bcur, u32* __restrict__ ebuf) {
    __shared__ int h[NB];
    __shared__ int base[NB];
    int t = threadIdx.x;
    if (t < NB) h[t] = 0;
    __syncthreads();
    int eb = blockIdx.x * 1024;
    int mb[4];
    u32 pk[4];
#pragma unroll
    for (int i = 0; i < 4; ++i) {
        int e = eb + i * 256 + t;
        if (e < NEDGES) {
            int d = dst[e];
            mb[i] = d >> 8;
            pk[i] = (u32)src[e] | ((u32)d << 16);
            atomicAdd(&h[mb[i]], 1);
        } else mb[i] = -1;
    }
    __syncthreads();
    if (t < NB) {
        int v = h[t];
        base[t] = v ? atomicAdd(&bcur[t], v) : 0;
        h[t] = 0;
    }
    __syncthreads();
#pragma unroll
    for (int i = 0; i < 4; ++i) {
        if (mb[i] >= 0) {
            int r = atomicAdd(&h[mb[i]], 1);
            ebuf[base[mb[i]] + r] = pk[i];
        }
    }
}

// per-bucket CSR finalize with per-node PHASE-SORTED edge lists
__global__ void __launch_bounds__(256) k_bfinal(
        const u32* __restrict__ ebuf, const int* __restrict__ boffs,
        int* __restrict__ offs, float* __restrict__ invd, int* __restrict__ csr) {
    __shared__ u32 se[ECAP];
    __shared__ int deg8[256 * NPH];
    __shared__ int s[256];
    int b = blockIdx.x, t = threadIdx.x;
    int nbase = b << 8;
    int ebeg = boffs[b], eend = boffs[b + 1];
    int ecnt = eend - ebeg;
#pragma unroll
    for (int j = 0; j < NPH; ++j) deg8[t * NPH + j] = 0;
    __syncthreads();
    for (int i = t; i < ecnt; i += 256) {
        u32 e = ebuf[ebeg + i];
        if (i < ECAP) se[i] = e;
        int dl = (int)(e >> 16) - nbase;
        int ph = (int)(e & 0xffffu) >> 13;
        atomicAdd(&deg8[dl * NPH + ph], 1);
    }
    __syncthreads();
    int pre[NPH];
    int run = 0;
#pragma unroll
    for (int j = 0; j < NPH; ++j) { pre[j] = run; run += deg8[t * NPH + j]; }
    int d = run;
    s[t] = d;
    __syncthreads();
    for (int off = 1; off < 256; off <<= 1) {
        int u = (t >= off) ? s[t - off] : 0;
        __syncthreads();
        s[t] += u;
        __syncthreads();
    }
    int ex = s[t] - d;
    int node = nbase + t;
    if (node < NNODES) {
        offs[node] = ebeg + ex;
        invd[node] = (d > 0) ? (1.0f / (float)d) : 0.0f;
    }
    __syncthreads();
#pragma unroll
    for (int j = 0; j < NPH; ++j) deg8[t * NPH + j] = ex + pre[j];
    __syncthreads();
    for (int i = t; i < ecnt; i += 256) {
        u32 e = (i < ECAP) ? se[i] : ebuf[ebeg + i];
        int dl = (int)(e >> 16) - nbase;
        int sv = (int)(e & 0xffffu);
        int r = atomicAdd(&deg8[dl * NPH + (sv >> 13)], 1);
        csr[ebeg + r] = sv;
    }
    if (b == 0 && t == 0) offs[NNODES] = NEDGES;
}

// ---------------- weight pack: [Wl|Wr] fp32 -> bf16 MFMA B-fragment layout ---
__global__ void k_pack(const float* __restrict__ Wl, const float* __restrict__ Wr,
                       u16* __restrict__ Bp) {
    int tid = blockIdx.x * 256 + threadIdx.x;  // 0..32767
    int j    = tid & 7;
    int lane = (tid >> 3) & 63;
    int ks   = (tid >> 9) & 3;
    int nt   = tid >> 11;
    int col  = nt * 16 + (lane & 15);
    int k    = ks * 32 + (lane >> 4) * 8 + j;
    float v = (col < FDIM) ? Wl[k * FDIM + col] : Wr[k * FDIM + (col - FDIM)];
    Bp[tid] = f2bf(v);
}

// ---------------- MFMA dual GEMM: y = in@Wl (bf16), zb = in@Wr + b (bf16) ----
// INF32=1: input fp32 (layer 0), cast fused into staging.
// B fragments prefetched to registers; epilogue staged through LDS for
// coalesced uint4 stores (8/thread instead of 64 scattered 2B stores/lane).
template <int INF32>
__global__ void __launch_bounds__(256) k_mfma(
        const void* __restrict__ in,
        const uint4* __restrict__ Bp,
        const float* __restrict__ bias,
        u16* __restrict__ y,
        u16* __restrict__ zb) {
    __shared__ u16 sA[64 * LPITCH];   // A-tile; reused as epilogue stage
    int t = threadIdx.x;
    int blk = blockIdx.x;
    int wave = t >> 6;
    int lane = t & 63;
    int m    = lane & 15;
    int quad = lane >> 4;

    // stage A-tile
    {
        int row = t >> 2;
        int q   = t & 3;
        int r = blk * 64 + row;
        if (r >= NNODES) r = NNODES - 1;
        if (INF32) {
            const float4* gs = (const float4*)((const float*)in + (size_t)r * FDIM) + q * 8;
            uint4* ld = (uint4*)(sA + row * LPITCH + q * 32);
#pragma unroll
            for (int i = 0; i < 4; ++i) {
                float4 a = gs[2 * i], b = gs[2 * i + 1];
                uint4 v;
                v.x = pack2(a.x, a.y); v.y = pack2(a.z, a.w);
                v.z = pack2(b.x, b.y); v.w = pack2(b.z, b.w);
                ld[i] = v;
            }
        } else {
            const uint4* gsrc = (const uint4*)((const u16*)in + (size_t)r * FDIM);
            uint4* ldst = (uint4*)(sA + row * LPITCH);
#pragma unroll
            for (int i = 0; i < 4; ++i) ldst[q * 4 + i] = gsrc[q * 4 + i];
        }
    }

    // prefetch all 16 B fragments (independent of LDS) while staging drains
    uint4 breg[4][4];   // [ks][nt]
#pragma unroll
    for (int ks = 0; ks < 4; ++ks)
#pragma unroll
        for (int nt = 0; nt < 4; ++nt)
            breg[ks][nt] = Bp[((wave * 4 + nt) * 4 + ks) * 64 + lane];

    __syncthreads();

    // A fragments from LDS
    bf16x8 a[4][4];
#pragma unroll
    for (int mt = 0; mt < 4; ++mt)
#pragma unroll
        for (int ks = 0; ks < 4; ++ks) {
            const uint4* ap = (const uint4*)(sA + (mt * 16 + m) * LPITCH + ks * 32 + quad * 8);
            a[mt][ks] = __builtin_bit_cast(bf16x8, *ap);
        }

    f32x4 acc[4][4];
#pragma unroll
    for (int mt = 0; mt < 4; ++mt)
#pragma unroll
        for (int nt = 0; nt < 4; ++nt) acc[mt][nt] = (f32x4){0.f, 0.f, 0.f, 0.f};

#pragma unroll
    for (int ks = 0; ks < 4; ++ks)
#pragma unroll
        for (int nt = 0; nt < 4; ++nt) {
            bf16x8 b = __builtin_bit_cast(bf16x8, breg[ks][nt]);
#pragma unroll
            for (int mt = 0; mt < 4; ++mt)
                acc[mt][nt] = __builtin_amdgcn_mfma_f32_16x16x32_bf16(
                    a[mt][ks], b, acc[mt][nt], 0, 0, 0);
        }

    // ---- epilogue: LDS transpose -> coalesced uint4 stores ----
    __syncthreads();   // sA (A-tile) dead
    // phase Y: waves 0,1 own cols 0..127 (the y half)
    if (wave < 2) {
#pragma unroll
        for (int nt = 0; nt < 4; ++nt) {
            int col = (wave * 4 + nt) * 16 + m;
#pragma unroll
            for (int mt = 0; mt < 4; ++mt)
#pragma unroll
                for (int r = 0; r < 4; ++r)
                    sA[(mt * 16 + quad * 4 + r) * LPITCH + col] = f2bf(acc[mt][nt][r]);
        }
    }
    __syncthreads();
#pragma unroll
    for (int i = 0; i < 4; ++i) {
        int g = i * 256 + t;
        int row = g >> 4, ch = g & 15;
        int gr = blk * 64 + row;
        if (gr < NNODES) {
            uint4 v = *(const uint4*)(sA + row * LPITCH + ch * 8);
            *((uint4*)(y + (size_t)gr * FDIM) + ch) = v;
        }
    }
    __syncthreads();
    // phase Z: waves 2,3 own cols 128..255 (the z half), add bias
    if (wave >= 2) {
#pragma unroll
        for (int nt = 0; nt < 4; ++nt) {
            int col = (wave * 4 + nt) * 16 + m - 128;
            float bv = bias[col];
#pragma unroll
            for (int mt = 0; mt < 4; ++mt)
#pragma unroll
                for (int r = 0; r < 4; ++r)
                    sA[(mt * 16 + quad * 4 + r) * LPITCH + col] = f2bf(acc[mt][nt][r] + bv);
        }
    }
    __syncthreads();
#pragma unroll
    for (int i = 0; i < 4; ++i) {
        int g = i * 256 + t;
        int row = g >> 4, ch = g & 15;
        int gr = blk * 64 + row;
        if (gr < NNODES) {
            uint4 v = *(const uint4*)(sA + row * LPITCH + ch * 8);
            *((uint4*)(zb + (size_t)gr * FDIM) + ch) = v;
        }
    }
}

// ---------------- gather aggregation + epilogue (128-wide) ----------------
template <int RELU, int OUTBF>
__global__ void k_agg(const u16* __restrict__ y,
                      const int* __restrict__ offs,
                      const int* __restrict__ csr,
                      const float* __restrict__ invd,
                      const u16* __restrict__ zb,
                      u16* __restrict__ outb,
                      float* __restrict__ outf) {
    int t = threadIdx.x;
    int nl = t >> 4, q = t & 15;
    int n = blockIdx.x * 16 + nl;
    int beg = offs[n], end = offs[n + 1];
    float a0 = 0, a1 = 0, a2 = 0, a3 = 0, a4 = 0, a5 = 0, a6 = 0, a7 = 0;
    const u16* yq = y + (size_t)q * 8;
    for (int i = beg; i < end; ++i) {
        int s = csr[i];
        uint4 v = *(const uint4*)(yq + (size_t)s * FDIM);
        a0 += bflo(v.x); a1 += bfhi(v.x);
        a2 += bflo(v.y); a3 += bfhi(v.y);
        a4 += bflo(v.z); a5 += bfhi(v.z);
        a6 += bflo(v.w); a7 += bfhi(v.w);
    }
    float iv = invd[n];
    uint4 zv = *(const uint4*)(zb + (size_t)n * FDIM + q * 8);
    float r0 = fmaf(a0, iv, bflo(zv.x)), r1 = fmaf(a1, iv, bfhi(zv.x));
    float r2 = fmaf(a2, iv, bflo(zv.y)), r3 = fmaf(a3, iv, bfhi(zv.y));
    float r4 = fmaf(a4, iv, bflo(zv.z)), r5 = fmaf(a5, iv, bfhi(zv.z));
    float r6 = fmaf(a6, iv, bflo(zv.w)), r7 = fmaf(a7, iv, bfhi(zv.w));
    if (RELU) {
        r0 = fmaxf(r0, 0.f); r1 = fmaxf(r1, 0.f); r2 = fmaxf(r2, 0.f); r3 = fmaxf(r3, 0.f);
        r4 = fmaxf(r4, 0.f); r5 = fmaxf(r5, 0.f); r6 = fmaxf(r6, 0.f); r7 = fmaxf(r7, 0.f);
    }
    if (OUTBF) {
        uint4 o;
        o.x = pack2(r0, r1); o.y = pack2(r2, r3);
        o.z = pack2(r4, r5); o.w = pack2(r6, r7);
        *(uint4*)(outb + (size_t)n * FDIM + q * 8) = o;
    } else {
        float* o = outf + (size_t)n * FDIM + q * 8;
        ((float4*)o)[0] = make_float4(r0, r1, r2, r3);
        ((float4*)o)[1] = make_float4(r4, r5, r6, r7);
    }
}

// ---------------- layer 2 transform ----------------
__global__ void k_gemm4(const float* __restrict__ h2,
                        const float* __restrict__ Wl,
                        const float* __restrict__ Wr,
                        const float* __restrict__ bias,
                        float* __restrict__ y4,
                        float* __restrict__ outz) {
    int tid = blockIdx.x * blockDim.x + threadIdx.x;
    int n = tid >> 2, c = tid & 3;
    if (n >= NNODES) return;
    const float4* row = (const float4*)(h2 + (size_t)n * FDIM);
    float a = 0, b = 0;
#pragma unroll 8
    for (int k4 = 0; k4 < 32; ++k4) {
        float4 v = row[k4];
        int k = k4 * 4;
        a = fmaf(v.x, Wl[(k + 0) * 4 + c], a); b = fmaf(v.x, Wr[(k + 0) * 4 + c], b);
        a = fmaf(v.y, Wl[(k + 1) * 4 + c], a); b = fmaf(v.y, Wr[(k + 1) * 4 + c], b);
        a = fmaf(v.z, Wl[(k + 2) * 4 + c], a); b = fmaf(v.z, Wr[(k + 2) * 4 + c], b);
        a = fmaf(v.w, Wl[(k + 3) * 4 + c], a); b = fmaf(v.w, Wr[(k + 3) * 4 + c], b);
    }
    y4[(size_t)n * 4 + c] = a;
    outz[(size_t)n * 4 + c] = b + bias[c];
}

// ---------------- layer 2 aggregation + duplicate write ----------------
__global__ void k_agg4(const float* __restrict__ y4,
                       const int* __restrict__ offs,
                       const int* __restrict__ csr,
                       const float* __restrict__ invd,
                       float* __restrict__ out) {
    int tid = blockIdx.x * blockDim.x + threadIdx.x;
    int n = tid >> 2, c = tid & 3;
    if (n >= NNODES) return;
    int beg = offs[n], end = offs[n + 1];
    float acc = 0;
    for (int i = beg; i < end; ++i) acc += y4[(size_t)csr[i] * 4 + c];
    float r = fmaf(acc, invd[n], out[(size_t)n * 4 + c]);
    out[(size_t)n * 4 + c] = r;
    out[(size_t)NNODES * NCLS + (size_t)n * 4 + c] = r;
}

extern "C" void kernel_launch(void* const* d_in, const int* in_sizes, int n_in,
                              void* d_out, int out_size, void* d_ws, size_t ws_size,
                              hipStream_t stream) {
    const float* x   = (const float*)d_in[0];
    const int* ei    = (const int*)d_in[1];
    const float* Wl0 = (const float*)d_in[2];
    const float* bl0 = (const float*)d_in[3];
    const float* Wr0 = (const float*)d_in[4];
    const float* Wl1 = (const float*)d_in[5];
    const float* bl1 = (const float*)d_in[6];
    const float* Wr1 = (const float*)d_in[7];
    const float* Wl2 = (const float*)d_in[8];
    const float* bl2 = (const float*)d_in[9];
    const float* Wr2 = (const float*)d_in[10];

    const int* src = ei;
    const int* dst = ei + NEDGES;

    float* out = (float*)d_out;
    float* h2  = out + 2 * (size_t)NNODES * NCLS;

    char* ws = (char*)d_ws;
    int*   offs = (int*)(ws + 0);
    float* invd = (float*)(ws + 200192);
    int*   bcnt = (int*)(ws + 400384);
    int*   boffs= (int*)(ws + 401408);
    int*   bcur = (int*)(ws + 402432);
    int*   csr  = (int*)(ws + 403456);
    u16*   y    = (u16*)(ws + 3603456);
    u16*   hb   = (u16*)(ws + 16403456);
    u16*   zb   = (u16*)(ws + 29203456);
    u32*   ebuf = (u32*)zb;                  // dead before zb is written
    float* y4   = (float*)(ws + 42003456);
    u16*   Bp0  = (u16*)(ws + 42803456);
    u16*   Bp1  = (u16*)(ws + 42868992);

    // ---- graph structure: bucketed CSR build (phase-sorted adjacency) ----
    hipMemsetAsync(bcnt, 0, NB * sizeof(int), stream);
    k_bhist<<<782, 256, 0, stream>>>(dst, bcnt);
    k_bscan<<<1, 256, 0, stream>>>(bcnt, boffs, bcur);
    k_bscatter<<<782, 256, 0, stream>>>(src, dst, bcur, ebuf);
    k_bfinal<<<NB, 256, 0, stream>>>(ebuf, boffs, offs, invd, csr);

    // ---- precompute packed weights ----
    k_pack<<<128, 256, 0, stream>>>(Wl0, Wr0, Bp0);
    k_pack<<<128, 256, 0, stream>>>(Wl1, Wr1, Bp1);

    const int mfmaBlocks = (NNODES + 63) / 64;  // 782

    // ---- layer 0 ----
    k_mfma<1><<<mfmaBlocks, 256, 0, stream>>>(x, (const uint4*)Bp0, bl0, y, zb);
    k_agg<1, 1><<<NNODES / 16, 256, 0, stream>>>(y, offs, csr, invd, zb, hb, nullptr);

    // ---- layer 1 ----
    k_mfma<0><<<mfmaBlocks, 256, 0, stream>>>(hb, (const uint4*)Bp1, bl1, y, zb);
    k_agg<0, 0><<<NNODES / 16, 256, 0, stream>>>(y, offs, csr, invd, zb, nullptr, h2);

    // ---- layer 2 ----
    k_gemm4<<<(NNODES * NCLS + 255) / 256, 256, 0, stream>>>(h2, Wl2, Wr2, bl2, y4, out);
    k_agg4<<<(NNODES * NCLS + 255) / 256, 256, 0, stream>>>(y4, offs, csr, invd, out);
}

// Round 8
// 260.030 us; speedup vs baseline: 17.4550x; 1.0944x over previous
//
#include <hip/hip_runtime.h>
#include <hip/hip_bf16.h>
#include <stdint.h>

#define NNODES 50000
#define NEDGES 800000
#define FDIM   128
#define NCLS   4
#define NB     196        // buckets of 256 nodes
#define ECAP   6144       // LDS edge-stage capacity per bucket (mean 4082)
#define LPITCH 136        // LDS row pitch in u16 (272B)
#define NPH    8          // source phases (src>>13) for gather L2 locality
#define SCAP   768        // LDS csr-slice capacity in k_agg (mean 256)

typedef uint32_t u32;
typedef unsigned short u16;
typedef __bf16 bf16x8 __attribute__((ext_vector_type(8)));
typedef float f32x4 __attribute__((ext_vector_type(4)));

__device__ __forceinline__ u16 f2bf(float f) {
    u32 u = __float_as_uint(f);
    u32 r = u + 0x7fffu + ((u >> 16) & 1u);
    return (u16)(r >> 16);
}
__device__ __forceinline__ u32 pack2(float a, float b) {
    return (u32)f2bf(a) | ((u32)f2bf(b) << 16);
}
__device__ __forceinline__ float bflo(u32 p) { return __uint_as_float(p << 16); }
__device__ __forceinline__ float bfhi(u32 p) { return __uint_as_float(p & 0xffff0000u); }

// ================= K1: bucket histogram + both weight packs =================
__global__ void __launch_bounds__(256) k_pre(
        const int* __restrict__ dst,
        const float* __restrict__ Wl0, const float* __restrict__ Wr0,
        const float* __restrict__ Wl1, const float* __restrict__ Wr1,
        int* __restrict__ bcnt, u16* __restrict__ Bp0, u16* __restrict__ Bp1) {
    int t = threadIdx.x;
    int bid = blockIdx.x;
    if (bid < 782) {                 // ---- bhist ----
        __shared__ int h[NB];
        if (t < NB) h[t] = 0;
        __syncthreads();
        int base = bid * 1024;
#pragma unroll
        for (int i = 0; i < 4; ++i) {
            int e = base + i * 256 + t;
            if (e < NEDGES) atomicAdd(&h[dst[e] >> 8], 1);
        }
        __syncthreads();
        if (t < NB) {
            int v = h[t];
            if (v) atomicAdd(&bcnt[t], v);
        }
    } else {                          // ---- weight pack (128 blocks per layer) ----
        int layer = (bid < 910) ? 0 : 1;
        int pid = bid - (layer ? 910 : 782);
        int tid = pid * 256 + t;      // 0..32767
        int j    = tid & 7;
        int lane = (tid >> 3) & 63;
        int ks   = (tid >> 9) & 3;
        int nt   = tid >> 11;
        int col  = nt * 16 + (lane & 15);
        int k    = ks * 32 + (lane >> 4) * 8 + j;
        const float* Wl = layer ? Wl1 : Wl0;
        const float* Wr = layer ? Wr1 : Wr0;
        float v = (col < FDIM) ? Wl[k * FDIM + col] : Wr[k * FDIM + (col - FDIM)];
        (layer ? Bp1 : Bp0)[tid] = f2bf(v);
    }
}

// ============ K2: layer-0 MFMA (blocks 0..781) + edge scatter (782..1563) ===
// NOTE: ebuf must NOT alias y or zb (both written by the MFMA half of this
// same dispatch). It aliases hb, which is first written later (K4).
__global__ void __launch_bounds__(256) k_scatmfma(
        const float* __restrict__ x, const uint4* __restrict__ Bp,
        const float* __restrict__ bias, u16* __restrict__ y, u16* __restrict__ zb,
        const int* __restrict__ src, const int* __restrict__ dst,
        const int* __restrict__ bcnt, int* __restrict__ bcur,
        u32* __restrict__ ebuf) {
    __shared__ u16 sA[64 * LPITCH];   // 17408 B; scatter half aliases ints onto it
    int t = threadIdx.x;
    if (blockIdx.x < 782) {
        // ---------------- MFMA dual GEMM, layer 0 (fp32 input) ----------------
        int blk = blockIdx.x;
        int wave = t >> 6, lane = t & 63, m = lane & 15, quad = lane >> 4;
        {
            int row = t >> 2, q = t & 3;
            int r = blk * 64 + row;
            if (r >= NNODES) r = NNODES - 1;
            const float4* gs = (const float4*)(x + (size_t)r * FDIM) + q * 8;
            uint4* ld = (uint4*)(sA + row * LPITCH + q * 32);
#pragma unroll
            for (int i = 0; i < 4; ++i) {
                float4 a = gs[2 * i], b = gs[2 * i + 1];
                uint4 v;
                v.x = pack2(a.x, a.y); v.y = pack2(a.z, a.w);
                v.z = pack2(b.x, b.y); v.w = pack2(b.z, b.w);
                ld[i] = v;
            }
        }
        uint4 breg[4][4];
#pragma unroll
        for (int ks = 0; ks < 4; ++ks)
#pragma unroll
            for (int nt = 0; nt < 4; ++nt)
                breg[ks][nt] = Bp[((wave * 4 + nt) * 4 + ks) * 64 + lane];
        __syncthreads();
        bf16x8 a[4][4];
#pragma unroll
        for (int mt = 0; mt < 4; ++mt)
#pragma unroll
            for (int ks = 0; ks < 4; ++ks)
                a[mt][ks] = __builtin_bit_cast(bf16x8,
                    *(const uint4*)(sA + (mt * 16 + m) * LPITCH + ks * 32 + quad * 8));
        f32x4 acc[4][4];
#pragma unroll
        for (int mt = 0; mt < 4; ++mt)
#pragma unroll
            for (int nt = 0; nt < 4; ++nt) acc[mt][nt] = (f32x4){0.f, 0.f, 0.f, 0.f};
#pragma unroll
        for (int ks = 0; ks < 4; ++ks)
#pragma unroll
            for (int nt = 0; nt < 4; ++nt) {
                bf16x8 b = __builtin_bit_cast(bf16x8, breg[ks][nt]);
#pragma unroll
                for (int mt = 0; mt < 4; ++mt)
                    acc[mt][nt] = __builtin_amdgcn_mfma_f32_16x16x32_bf16(
                        a[mt][ks], b, acc[mt][nt], 0, 0, 0);
            }
        __syncthreads();
        if (wave < 2) {
#pragma unroll
            for (int nt = 0; nt < 4; ++nt) {
                int col = (wave * 4 + nt) * 16 + m;
#pragma unroll
                for (int mt = 0; mt < 4; ++mt)
#pragma unroll
                    for (int r = 0; r < 4; ++r)
                        sA[(mt * 16 + quad * 4 + r) * LPITCH + col] = f2bf(acc[mt][nt][r]);
            }
        }
        __syncthreads();
#pragma unroll
        for (int i = 0; i < 4; ++i) {
            int g = i * 256 + t, row = g >> 4, ch = g & 15;
            int gr = blk * 64 + row;
            if (gr < NNODES)
                *((uint4*)(y + (size_t)gr * FDIM) + ch) =
                    *(const uint4*)(sA + row * LPITCH + ch * 8);
        }
        __syncthreads();
        if (wave >= 2) {
#pragma unroll
            for (int nt = 0; nt < 4; ++nt) {
                int col = (wave * 4 + nt) * 16 + m - 128;
                float bv = bias[col];
#pragma unroll
                for (int mt = 0; mt < 4; ++mt)
#pragma unroll
                    for (int r = 0; r < 4; ++r)
                        sA[(mt * 16 + quad * 4 + r) * LPITCH + col] = f2bf(acc[mt][nt][r] + bv);
            }
        }
        __syncthreads();
#pragma unroll
        for (int i = 0; i < 4; ++i) {
            int g = i * 256 + t, row = g >> 4, ch = g & 15;
            int gr = blk * 64 + row;
            if (gr < NNODES)
                *((uint4*)(zb + (size_t)gr * FDIM) + ch) =
                    *(const uint4*)(sA + row * LPITCH + ch * 8);
        }
    } else {
        // ---------------- edge bucket scatter (with in-LDS bucket scan) -------
        int* hh = (int*)sA;           // [256]
        int* bb = hh + 256;           // [256]
        int* ss = bb + 256;           // [256]
        int v = (t < NB) ? bcnt[t] : 0;
        ss[t] = v;
        __syncthreads();
        for (int off = 1; off < 256; off <<= 1) {
            int u = (t >= off) ? ss[t - off] : 0;
            __syncthreads();
            ss[t] += u;
            __syncthreads();
        }
        int boff = ss[t] - v;         // exclusive bucket start
        hh[t] = 0;
        __syncthreads();
        int eb = (blockIdx.x - 782) * 1024;
        int mb[4];
        u32 pk[4];
#pragma unroll
        for (int i = 0; i < 4; ++i) {
            int e = eb + i * 256 + t;
            if (e < NEDGES) {
                int d = dst[e];
                mb[i] = d >> 8;
                pk[i] = (u32)src[e] | ((u32)d << 16);
                atomicAdd(&hh[mb[i]], 1);
            } else mb[i] = -1;
        }
        __syncthreads();
        if (t < NB) {
            int c = hh[t];
            bb[t] = c ? (boff + atomicAdd(&bcur[t], c)) : 0;
            hh[t] = 0;
        }
        __syncthreads();
#pragma unroll
        for (int i = 0; i < 4; ++i) {
            if (mb[i] >= 0) {
                int r = atomicAdd(&hh[mb[i]], 1);
                ebuf[bb[mb[i]] + r] = pk[i];
            }
        }
    }
}

// ======= K3: per-bucket CSR finalize, phase-sorted (self-scans bcnt) ========
__global__ void __launch_bounds__(256) k_bfinal(
        const u32* __restrict__ ebuf, const int* __restrict__ bcnt,
        int* __restrict__ offs, float* __restrict__ invd, int* __restrict__ csr) {
    __shared__ u32 se[ECAP];
    __shared__ int deg8[256 * NPH];
    __shared__ int s[256];
    int b = blockIdx.x, t = threadIdx.x;
    int nbase = b << 8;
    int v = (t < NB) ? bcnt[t] : 0;
    s[t] = v;
    __syncthreads();
    for (int off = 1; off < 256; off <<= 1) {
        int u = (t >= off) ? s[t - off] : 0;
        __syncthreads();
        s[t] += u;
        __syncthreads();
    }
    int ebeg = s[b] - bcnt[b];
    int ecnt = bcnt[b];
    __syncthreads();
#pragma unroll
    for (int j = 0; j < NPH; ++j) deg8[t * NPH + j] = 0;
    __syncthreads();
    for (int i = t; i < ecnt; i += 256) {
        u32 e = ebuf[ebeg + i];
        if (i < ECAP) se[i] = e;
        atomicAdd(&deg8[((int)(e >> 16) - nbase) * NPH + (((int)(e & 0xffffu)) >> 13)], 1);
    }
    __syncthreads();
    int pre[NPH];
    int run = 0;
#pragma unroll
    for (int j = 0; j < NPH; ++j) { pre[j] = run; run += deg8[t * NPH + j]; }
    int d = run;
    s[t] = d;
    __syncthreads();
    for (int off = 1; off < 256; off <<= 1) {
        int u = (t >= off) ? s[t - off] : 0;
        __syncthreads();
        s[t] += u;
        __syncthreads();
    }
    int ex = s[t] - d;
    int node = nbase + t;
    if (node < NNODES) {
        offs[node] = ebeg + ex;
        invd[node] = (d > 0) ? (1.0f / (float)d) : 0.0f;
    }
    __syncthreads();
#pragma unroll
    for (int j = 0; j < NPH; ++j) deg8[t * NPH + j] = ex + pre[j];
    __syncthreads();
    for (int i = t; i < ecnt; i += 256) {
        u32 e = (i < ECAP) ? se[i] : ebuf[ebeg + i];
        int dl = (int)(e >> 16) - nbase;
        int sv = (int)(e & 0xffffu);
        int r = atomicAdd(&deg8[dl * NPH + (sv >> 13)], 1);
        csr[ebeg + r] = sv;
    }
    if (b == 0 && t == 0) offs[NNODES] = NEDGES;
}

// ===== K4/K6: gather aggregation (+ optional fused final-layer transform) ===
template <int RELU, int OUTBF, int FUSE4>
__global__ void __launch_bounds__(256) k_agg(
        const u16* __restrict__ y, const int* __restrict__ offs,
        const int* __restrict__ csr, const float* __restrict__ invd,
        const u16* __restrict__ zb, u16* __restrict__ outb, float* __restrict__ outf,
        const float* __restrict__ Wl2, const float* __restrict__ Wr2,
        const float* __restrict__ bl2, float* __restrict__ y4,
        float* __restrict__ outz) {
    __shared__ int sidx[SCAP];
    int t = threadIdx.x;
    int n0 = blockIdx.x * 16;
    int base0 = offs[n0];
    int ecnt = offs[n0 + 16] - base0;
    for (int i = t; i < ecnt && i < SCAP; i += 256) sidx[i] = csr[base0 + i];
    __syncthreads();
    int nl = t >> 4, q = t & 15;
    int n = n0 + nl;
    int beg = offs[n], end = offs[n + 1];
    float a0 = 0, a1 = 0, a2 = 0, a3 = 0, a4 = 0, a5 = 0, a6 = 0, a7 = 0;
    const u16* yq = y + (size_t)q * 8;
    for (int ii = beg; ii < end; ++ii) {
        int li = ii - base0;
        int s = (li < SCAP) ? sidx[li] : csr[ii];
        uint4 v = *(const uint4*)(yq + (size_t)s * FDIM);
        a0 += bflo(v.x); a1 += bfhi(v.x);
        a2 += bflo(v.y); a3 += bfhi(v.y);
        a4 += bflo(v.z); a5 += bfhi(v.z);
        a6 += bflo(v.w); a7 += bfhi(v.w);
    }
    float iv = invd[n];
    uint4 zv = *(const uint4*)(zb + (size_t)n * FDIM + q * 8);
    float r0 = fmaf(a0, iv, bflo(zv.x)), r1 = fmaf(a1, iv, bfhi(zv.x));
    float r2 = fmaf(a2, iv, bflo(zv.y)), r3 = fmaf(a3, iv, bfhi(zv.y));
    float r4 = fmaf(a4, iv, bflo(zv.z)), r5 = fmaf(a5, iv, bfhi(zv.z));
    float r6 = fmaf(a6, iv, bflo(zv.w)), r7 = fmaf(a7, iv, bfhi(zv.w));
    if (RELU) {
        r0 = fmaxf(r0, 0.f); r1 = fmaxf(r1, 0.f); r2 = fmaxf(r2, 0.f); r3 = fmaxf(r3, 0.f);
        r4 = fmaxf(r4, 0.f); r5 = fmaxf(r5, 0.f); r6 = fmaxf(r6, 0.f); r7 = fmaxf(r7, 0.f);
    }
    if (OUTBF) {
        uint4 o;
        o.x = pack2(r0, r1); o.y = pack2(r2, r3);
        o.z = pack2(r4, r5); o.w = pack2(r6, r7);
        *(uint4*)(outb + (size_t)n * FDIM + q * 8) = o;
    } else {
        float* o = outf + (size_t)n * FDIM + q * 8;
        ((float4*)o)[0] = make_float4(r0, r1, r2, r3);
        ((float4*)o)[1] = make_float4(r4, r5, r6, r7);
    }
    if (FUSE4) {
        // y4 = h2@Wl2, outz = h2@Wr2 + bl2 via 16-lane shuffle reduction
        float rr[8] = {r0, r1, r2, r3, r4, r5, r6, r7};
        float4 py = {0, 0, 0, 0}, pz = {0, 0, 0, 0};
        const float4* wl4 = (const float4*)Wl2;  // [128] rows of 4
        const float4* wr4 = (const float4*)Wr2;
#pragma unroll
        for (int j = 0; j < 8; ++j) {
            float4 wl = wl4[q * 8 + j], wr = wr4[q * 8 + j];
            py.x += rr[j] * wl.x; py.y += rr[j] * wl.y;
            py.z += rr[j] * wl.z; py.w += rr[j] * wl.w;
            pz.x += rr[j] * wr.x; pz.y += rr[j] * wr.y;
            pz.z += rr[j] * wr.z; pz.w += rr[j] * wr.w;
        }
#pragma unroll
        for (int off = 1; off < 16; off <<= 1) {
            py.x += __shfl_xor(py.x, off, 16); py.y += __shfl_xor(py.y, off, 16);
            py.z += __shfl_xor(py.z, off, 16); py.w += __shfl_xor(py.w, off, 16);
            pz.x += __shfl_xor(pz.x, off, 16); pz.y += __shfl_xor(pz.y, off, 16);
            pz.z += __shfl_xor(pz.z, off, 16); pz.w += __shfl_xor(pz.w, off, 16);
        }
        if (q == 0) {
            ((float4*)y4)[n] = py;
            float4 b2 = *(const float4*)bl2;
            float4 o;
            o.x = pz.x + b2.x; o.y = pz.y + b2.y;
            o.z = pz.z + b2.z; o.w = pz.w + b2.w;
            ((float4*)outz)[n] = o;
        }
    }
}

// ================= K5: layer-1 MFMA (bf16 input) ============================
__global__ void __launch_bounds__(256) k_mfma1(
        const u16* __restrict__ in, const uint4* __restrict__ Bp,
        const float* __restrict__ bias, u16* __restrict__ y, u16* __restrict__ zb) {
    __shared__ u16 sA[64 * LPITCH];
    int t = threadIdx.x;
    int blk = blockIdx.x;
    int wave = t >> 6, lane = t & 63, m = lane & 15, quad = lane >> 4;
    {
        int row = t >> 2, q = t & 3;
        int r = blk * 64 + row;
        if (r >= NNODES) r = NNODES - 1;
        const uint4* gsrc = (const uint4*)(in + (size_t)r * FDIM);
        uint4* ldst = (uint4*)(sA + row * LPITCH);
#pragma unroll
        for (int i = 0; i < 4; ++i) ldst[q * 4 + i] = gsrc[q * 4 + i];
    }
    uint4 breg[4][4];
#pragma unroll
    for (int ks = 0; ks < 4; ++ks)
#pragma unroll
        for (int nt = 0; nt < 4; ++nt)
            breg[ks][nt] = Bp[((wave * 4 + nt) * 4 + ks) * 64 + lane];
    __syncthreads();
    bf16x8 a[4][4];
#pragma unroll
    for (int mt = 0; mt < 4; ++mt)
#pragma unroll
        for (int ks = 0; ks < 4; ++ks)
            a[mt][ks] = __builtin_bit_cast(bf16x8,
                *(const uint4*)(sA + (mt * 16 + m) * LPITCH + ks * 32 + quad * 8));
    f32x4 acc[4][4];
#pragma unroll
    for (int mt = 0; mt < 4; ++mt)
#pragma unroll
        for (int nt = 0; nt < 4; ++nt) acc[mt][nt] = (f32x4){0.f, 0.f, 0.f, 0.f};
#pragma unroll
    for (int ks = 0; ks < 4; ++ks)
#pragma unroll
        for (int nt = 0; nt < 4; ++nt) {
            bf16x8 b = __builtin_bit_cast(bf16x8, breg[ks][nt]);
#pragma unroll
            for (int mt = 0; mt < 4; ++mt)
                acc[mt][nt] = __builtin_amdgcn_mfma_f32_16x16x32_bf16(
                    a[mt][ks], b, acc[mt][nt], 0, 0, 0);
        }
    __syncthreads();
    if (wave < 2) {
#pragma unroll
        for (int nt = 0; nt < 4; ++nt) {
            int col = (wave * 4 + nt) * 16 + m;
#pragma unroll
            for (int mt = 0; mt < 4; ++mt)
#pragma unroll
                for (int r = 0; r < 4; ++r)
                    sA[(mt * 16 + quad * 4 + r) * LPITCH + col] = f2bf(acc[mt][nt][r]);
        }
    }
    __syncthreads();
#pragma unroll
    for (int i = 0; i < 4; ++i) {
        int g = i * 256 + t, row = g >> 4, ch = g & 15;
        int gr = blk * 64 + row;
        if (gr < NNODES)
            *((uint4*)(y + (size_t)gr * FDIM) + ch) =
                *(const uint4*)(sA + row * LPITCH + ch * 8);
    }
    __syncthreads();
    if (wave >= 2) {
#pragma unroll
        for (int nt = 0; nt < 4; ++nt) {
            int col = (wave * 4 + nt) * 16 + m - 128;
            float bv = bias[col];
#pragma unroll
            for (int mt = 0; mt < 4; ++mt)
#pragma unroll
                for (int r = 0; r < 4; ++r)
                    sA[(mt * 16 + quad * 4 + r) * LPITCH + col] = f2bf(acc[mt][nt][r] + bv);
        }
    }
    __syncthreads();
#pragma unroll
    for (int i = 0; i < 4; ++i) {
        int g = i * 256 + t, row = g >> 4, ch = g & 15;
        int gr = blk * 64 + row;
        if (gr < NNODES)
            *((uint4*)(zb + (size_t)gr * FDIM) + ch) =
                *(const uint4*)(sA + row * LPITCH + ch * 8);
    }
}

// ================= K7: final 4-wide aggregation + duplicate write ===========
__global__ void k_agg4(const float* __restrict__ y4,
                       const int* __restrict__ offs,
                       const int* __restrict__ csr,
                       const float* __restrict__ invd,
                       float* __restrict__ out) {
    int tid = blockIdx.x * blockDim.x + threadIdx.x;
    int n = tid >> 2, c = tid & 3;
    if (n >= NNODES) return;
    int beg = offs[n], end = offs[n + 1];
    float acc = 0;
    for (int i = beg; i < end; ++i) acc += y4[(size_t)csr[i] * 4 + c];
    float r = fmaf(acc, invd[n], out[(size_t)n * 4 + c]);
    out[(size_t)n * 4 + c] = r;
    out[(size_t)NNODES * NCLS + (size_t)n * 4 + c] = r;
}

extern "C" void kernel_launch(void* const* d_in, const int* in_sizes, int n_in,
                              void* d_out, int out_size, void* d_ws, size_t ws_size,
                              hipStream_t stream) {
    const float* x   = (const float*)d_in[0];
    const int* ei    = (const int*)d_in[1];
    const float* Wl0 = (const float*)d_in[2];
    const float* bl0 = (const float*)d_in[3];
    const float* Wr0 = (const float*)d_in[4];
    const float* Wl1 = (const float*)d_in[5];
    const float* bl1 = (const float*)d_in[6];
    const float* Wr1 = (const float*)d_in[7];
    const float* Wl2 = (const float*)d_in[8];
    const float* bl2 = (const float*)d_in[9];
    const float* Wr2 = (const float*)d_in[10];

    const int* src = ei;
    const int* dst = ei + NEDGES;

    float* out = (float*)d_out;
    float* h2  = out + 2 * (size_t)NNODES * NCLS;

    char* ws = (char*)d_ws;
    int*   offs = (int*)(ws + 0);              // 50001 ints
    float* invd = (float*)(ws + 200192);       // N floats
    int*   bcnt = (int*)(ws + 400384);         // NB ints
    int*   bcur = (int*)(ws + 401408);         // NB ints (memset with bcnt)
    int*   csr  = (int*)(ws + 402432);         // E ints
    u16*   y    = (u16*)(ws + 3602432);        // N*128 bf16
    u16*   hb   = (u16*)(ws + 16402432);       // N*128 bf16
    u16*   zb   = (u16*)(ws + 29202432);       // N*128 bf16
    u32*   ebuf = (u32*)hb;                    // E u32 aliases hb: written K2,
                                               // consumed K3; hb first written K4
    float* y4   = (float*)(ws + 42002432);     // N*4 floats
    u16*   Bp0  = (u16*)(ws + 42802432);       // 32768 bf16
    u16*   Bp1  = (u16*)(ws + 42867968);       // 32768 bf16

    hipMemsetAsync(bcnt, 0, 2048, stream);     // bcnt + bcur

    // K1: bucket histogram + pack both layers' weights
    k_pre<<<1038, 256, 0, stream>>>(dst, Wl0, Wr0, Wl1, Wr1, bcnt, Bp0, Bp1);

    // K2: layer-0 MFMA + edge bucket scatter
    k_scatmfma<<<1564, 256, 0, stream>>>(x, (const uint4*)Bp0, bl0, y, zb,
                                         src, dst, bcnt, bcur, ebuf);

    // K3: per-bucket CSR finalize (phase-sorted)
    k_bfinal<<<NB, 256, 0, stream>>>(ebuf, bcnt, offs, invd, csr);

    // K4: layer-0 aggregation (relu, bf16 out)
    k_agg<1, 1, 0><<<NNODES / 16, 256, 0, stream>>>(
        y, offs, csr, invd, zb, hb, nullptr,
        nullptr, nullptr, nullptr, nullptr, nullptr);

    // K5: layer-1 MFMA
    k_mfma1<<<(NNODES + 63) / 64, 256, 0, stream>>>(hb, (const uint4*)Bp1, bl1, y, zb);

    // K6: layer-1 aggregation (fp32 h2 out) + fused final-layer transform
    k_agg<0, 0, 1><<<NNODES / 16, 256, 0, stream>>>(
        y, offs, csr, invd, zb, nullptr, h2,
        Wl2, Wr2, bl2, y4, out);

    // K7: final aggregation, duplicate write
    k_agg4<<<(NNODES * NCLS + 255) / 256, 256, 0, stream>>>(y4, offs, csr, invd, out);
}

// Round 9
// 247.466 us; speedup vs baseline: 18.3412x; 1.0508x over previous
//
#include <hip/hip_runtime.h>
#include <hip/hip_bf16.h>
#include <stdint.h>

#define NNODES 50000
#define NEDGES 800000
#define FDIM   128
#define NCLS   4
#define NB     196        // buckets of 256 nodes
#define ECAP   6144       // LDS edge-stage capacity per bucket (mean 4082)
#define LPITCH 136        // LDS row pitch in u16 (272B)
#define NPH    8          // source phases (src>>13) for gather L2 locality
#define SCAP   768        // LDS csr-slice capacity in k_agg (mean 256)

typedef uint32_t u32;
typedef unsigned short u16;
typedef __bf16 bf16x8 __attribute__((ext_vector_type(8)));
typedef float f32x4 __attribute__((ext_vector_type(4)));

__device__ __forceinline__ u16 f2bf(float f) {
    u32 u = __float_as_uint(f);
    u32 r = u + 0x7fffu + ((u >> 16) & 1u);
    return (u16)(r >> 16);
}
__device__ __forceinline__ u32 pack2(float a, float b) {
    return (u32)f2bf(a) | ((u32)f2bf(b) << 16);
}
__device__ __forceinline__ float bflo(u32 p) { return __uint_as_float(p << 16); }
__device__ __forceinline__ float bfhi(u32 p) { return __uint_as_float(p & 0xffff0000u); }

// ================= K1: bucket histogram + both weight packs =================
__global__ void __launch_bounds__(256) k_pre(
        const int* __restrict__ dst,
        const float* __restrict__ Wl0, const float* __restrict__ Wr0,
        const float* __restrict__ Wl1, const float* __restrict__ Wr1,
        int* __restrict__ bcnt, u16* __restrict__ Bp0, u16* __restrict__ Bp1) {
    int t = threadIdx.x;
    int bid = blockIdx.x;
    if (bid < 782) {                 // ---- bhist ----
        __shared__ int h[NB];
        if (t < NB) h[t] = 0;
        __syncthreads();
        int base = bid * 1024;
#pragma unroll
        for (int i = 0; i < 4; ++i) {
            int e = base + i * 256 + t;
            if (e < NEDGES) atomicAdd(&h[dst[e] >> 8], 1);
        }
        __syncthreads();
        if (t < NB) {
            int v = h[t];
            if (v) atomicAdd(&bcnt[t], v);
        }
    } else {                          // ---- weight pack (128 blocks per layer) ----
        int layer = (bid < 910) ? 0 : 1;
        int pid = bid - (layer ? 910 : 782);
        int tid = pid * 256 + t;      // 0..32767
        int j    = tid & 7;
        int lane = (tid >> 3) & 63;
        int ks   = (tid >> 9) & 3;
        int nt   = tid >> 11;
        int col  = nt * 16 + (lane & 15);
        int k    = ks * 32 + (lane >> 4) * 8 + j;
        const float* Wl = layer ? Wl1 : Wl0;
        const float* Wr = layer ? Wr1 : Wr0;
        float v = (col < FDIM) ? Wl[k * FDIM + col] : Wr[k * FDIM + (col - FDIM)];
        (layer ? Bp1 : Bp0)[tid] = f2bf(v);
    }
}

// ============ K2: layer-0 MFMA (blocks 0..781) + edge scatter (782..1563) ===
// NOTE: ebuf aliases hb (first written in K4) — must NOT alias y/zb.
__global__ void __launch_bounds__(256) k_scatmfma(
        const float* __restrict__ x, const uint4* __restrict__ Bp,
        const float* __restrict__ bias, u16* __restrict__ y, u16* __restrict__ zb,
        const int* __restrict__ src, const int* __restrict__ dst,
        const int* __restrict__ bcnt, int* __restrict__ bcur,
        u32* __restrict__ ebuf) {
    __shared__ u16 sA[64 * LPITCH];   // 17408 B; scatter half aliases ints onto it
    int t = threadIdx.x;
    if (blockIdx.x < 782) {
        // ---------------- MFMA dual GEMM, layer 0 (fp32 input) ----------------
        int blk = blockIdx.x;
        int wave = t >> 6, lane = t & 63, m = lane & 15, quad = lane >> 4;
        {
            int row = t >> 2, q = t & 3;
            int r = blk * 64 + row;
            if (r >= NNODES) r = NNODES - 1;
            const float4* gs = (const float4*)(x + (size_t)r * FDIM) + q * 8;
            uint4* ld = (uint4*)(sA + row * LPITCH + q * 32);
#pragma unroll
            for (int i = 0; i < 4; ++i) {
                float4 a = gs[2 * i], b = gs[2 * i + 1];
                uint4 v;
                v.x = pack2(a.x, a.y); v.y = pack2(a.z, a.w);
                v.z = pack2(b.x, b.y); v.w = pack2(b.z, b.w);
                ld[i] = v;
            }
        }
        uint4 breg[4][4];
#pragma unroll
        for (int ks = 0; ks < 4; ++ks)
#pragma unroll
            for (int nt = 0; nt < 4; ++nt)
                breg[ks][nt] = Bp[((wave * 4 + nt) * 4 + ks) * 64 + lane];
        __syncthreads();
        bf16x8 a[4][4];
#pragma unroll
        for (int mt = 0; mt < 4; ++mt)
#pragma unroll
            for (int ks = 0; ks < 4; ++ks)
                a[mt][ks] = __builtin_bit_cast(bf16x8,
                    *(const uint4*)(sA + (mt * 16 + m) * LPITCH + ks * 32 + quad * 8));
        f32x4 acc[4][4];
#pragma unroll
        for (int mt = 0; mt < 4; ++mt)
#pragma unroll
            for (int nt = 0; nt < 4; ++nt) acc[mt][nt] = (f32x4){0.f, 0.f, 0.f, 0.f};
#pragma unroll
        for (int ks = 0; ks < 4; ++ks)
#pragma unroll
            for (int nt = 0; nt < 4; ++nt) {
                bf16x8 b = __builtin_bit_cast(bf16x8, breg[ks][nt]);
#pragma unroll
                for (int mt = 0; mt < 4; ++mt)
                    acc[mt][nt] = __builtin_amdgcn_mfma_f32_16x16x32_bf16(
                        a[mt][ks], b, acc[mt][nt], 0, 0, 0);
            }
        __syncthreads();
        if (wave < 2) {
#pragma unroll
            for (int nt = 0; nt < 4; ++nt) {
                int col = (wave * 4 + nt) * 16 + m;
#pragma unroll
                for (int mt = 0; mt < 4; ++mt)
#pragma unroll
                    for (int r = 0; r < 4; ++r)
                        sA[(mt * 16 + quad * 4 + r) * LPITCH + col] = f2bf(acc[mt][nt][r]);
            }
        }
        __syncthreads();
#pragma unroll
        for (int i = 0; i < 4; ++i) {
            int g = i * 256 + t, row = g >> 4, ch = g & 15;
            int gr = blk * 64 + row;
            if (gr < NNODES)
                *((uint4*)(y + (size_t)gr * FDIM) + ch) =
                    *(const uint4*)(sA + row * LPITCH + ch * 8);
        }
        __syncthreads();
        if (wave >= 2) {
#pragma unroll
            for (int nt = 0; nt < 4; ++nt) {
                int col = (wave * 4 + nt) * 16 + m - 128;
                float bv = bias[col];
#pragma unroll
                for (int mt = 0; mt < 4; ++mt)
#pragma unroll
                    for (int r = 0; r < 4; ++r)
                        sA[(mt * 16 + quad * 4 + r) * LPITCH + col] = f2bf(acc[mt][nt][r] + bv);
            }
        }
        __syncthreads();
#pragma unroll
        for (int i = 0; i < 4; ++i) {
            int g = i * 256 + t, row = g >> 4, ch = g & 15;
            int gr = blk * 64 + row;
            if (gr < NNODES)
                *((uint4*)(zb + (size_t)gr * FDIM) + ch) =
                    *(const uint4*)(sA + row * LPITCH + ch * 8);
        }
    } else {
        // ---------------- edge bucket scatter (with in-LDS bucket scan) -------
        int* hh = (int*)sA;           // [256]
        int* bb = hh + 256;           // [256]
        int* ss = bb + 256;           // [256]
        int v = (t < NB) ? bcnt[t] : 0;
        ss[t] = v;
        __syncthreads();
        for (int off = 1; off < 256; off <<= 1) {
            int u = (t >= off) ? ss[t - off] : 0;
            __syncthreads();
            ss[t] += u;
            __syncthreads();
        }
        int boff = ss[t] - v;         // exclusive bucket start
        hh[t] = 0;
        __syncthreads();
        int eb = (blockIdx.x - 782) * 1024;
        int mb[4];
        u32 pk[4];
#pragma unroll
        for (int i = 0; i < 4; ++i) {
            int e = eb + i * 256 + t;
            if (e < NEDGES) {
                int d = dst[e];
                mb[i] = d >> 8;
                pk[i] = (u32)src[e] | ((u32)d << 16);
                atomicAdd(&hh[mb[i]], 1);
            } else mb[i] = -1;
        }
        __syncthreads();
        if (t < NB) {
            int c = hh[t];
            bb[t] = c ? (boff + atomicAdd(&bcur[t], c)) : 0;
            hh[t] = 0;
        }
        __syncthreads();
#pragma unroll
        for (int i = 0; i < 4; ++i) {
            if (mb[i] >= 0) {
                int r = atomicAdd(&hh[mb[i]], 1);
                ebuf[bb[mb[i]] + r] = pk[i];
            }
        }
    }
}

// ======= K3: per-bucket CSR finalize, phase-sorted (self-scans bcnt) ========
__global__ void __launch_bounds__(256) k_bfinal(
        const u32* __restrict__ ebuf, const int* __restrict__ bcnt,
        int* __restrict__ offs, float* __restrict__ invd, int* __restrict__ csr) {
    __shared__ u32 se[ECAP];
    __shared__ int deg8[256 * NPH];
    __shared__ int s[256];
    int b = blockIdx.x, t = threadIdx.x;
    int nbase = b << 8;
    int v = (t < NB) ? bcnt[t] : 0;
    s[t] = v;
    __syncthreads();
    for (int off = 1; off < 256; off <<= 1) {
        int u = (t >= off) ? s[t - off] : 0;
        __syncthreads();
        s[t] += u;
        __syncthreads();
    }
    int ebeg = s[b] - bcnt[b];
    int ecnt = bcnt[b];
    __syncthreads();
#pragma unroll
    for (int j = 0; j < NPH; ++j) deg8[t * NPH + j] = 0;
    __syncthreads();
    for (int i = t; i < ecnt; i += 256) {
        u32 e = ebuf[ebeg + i];
        if (i < ECAP) se[i] = e;
        atomicAdd(&deg8[((int)(e >> 16) - nbase) * NPH + (((int)(e & 0xffffu)) >> 13)], 1);
    }
    __syncthreads();
    int pre[NPH];
    int run = 0;
#pragma unroll
    for (int j = 0; j < NPH; ++j) { pre[j] = run; run += deg8[t * NPH + j]; }
    int d = run;
    s[t] = d;
    __syncthreads();
    for (int off = 1; off < 256; off <<= 1) {
        int u = (t >= off) ? s[t - off] : 0;
        __syncthreads();
        s[t] += u;
        __syncthreads();
    }
    int ex = s[t] - d;
    int node = nbase + t;
    if (node < NNODES) {
        offs[node] = ebeg + ex;
        invd[node] = (d > 0) ? (1.0f / (float)d) : 0.0f;
    }
    __syncthreads();
#pragma unroll
    for (int j = 0; j < NPH; ++j) deg8[t * NPH + j] = ex + pre[j];
    __syncthreads();
    for (int i = t; i < ecnt; i += 256) {
        u32 e = (i < ECAP) ? se[i] : ebuf[ebeg + i];
        int dl = (int)(e >> 16) - nbase;
        int sv = (int)(e & 0xffffu);
        int r = atomicAdd(&deg8[dl * NPH + (sv >> 13)], 1);
        csr[ebeg + r] = sv;
    }
    if (b == 0 && t == 0) offs[NNODES] = NEDGES;
}

// ===== K4/K6: gather aggregation (+ optional fused final-layer transform) ===
// Gather loop manually unrolled x4: 4 independent uint4 loads in flight.
template <int RELU, int OUTBF, int FUSE4>
__global__ void __launch_bounds__(256) k_agg(
        const u16* __restrict__ y, const int* __restrict__ offs,
        const int* __restrict__ csr, const float* __restrict__ invd,
        const u16* __restrict__ zb, u16* __restrict__ outb, float* __restrict__ outf,
        const float* __restrict__ Wl2, const float* __restrict__ Wr2,
        const float* __restrict__ bl2, float* __restrict__ y4,
        float* __restrict__ outz) {
    __shared__ int sidx[SCAP];
    int t = threadIdx.x;
    int n0 = blockIdx.x * 16;
    int base0 = offs[n0];
    int ecnt = offs[n0 + 16] - base0;
    for (int i = t; i < ecnt && i < SCAP; i += 256) sidx[i] = csr[base0 + i];
    __syncthreads();
    int nl = t >> 4, q = t & 15;
    int n = n0 + nl;
    int beg = offs[n], end = offs[n + 1];
    float a0 = 0, a1 = 0, a2 = 0, a3 = 0, a4 = 0, a5 = 0, a6 = 0, a7 = 0;
    const u16* yq = y + (size_t)q * 8;
    int ii = beg;
    for (; ii + 4 <= end; ii += 4) {
        int li = ii - base0;
        int s0, s1, s2, s3;
        if (li + 3 < SCAP) {
            s0 = sidx[li]; s1 = sidx[li + 1]; s2 = sidx[li + 2]; s3 = sidx[li + 3];
        } else {
            s0 = csr[ii]; s1 = csr[ii + 1]; s2 = csr[ii + 2]; s3 = csr[ii + 3];
        }
        uint4 v0 = *(const uint4*)(yq + (size_t)s0 * FDIM);
        uint4 v1 = *(const uint4*)(yq + (size_t)s1 * FDIM);
        uint4 v2 = *(const uint4*)(yq + (size_t)s2 * FDIM);
        uint4 v3 = *(const uint4*)(yq + (size_t)s3 * FDIM);
        a0 += bflo(v0.x); a1 += bfhi(v0.x); a2 += bflo(v0.y); a3 += bfhi(v0.y);
        a4 += bflo(v0.z); a5 += bfhi(v0.z); a6 += bflo(v0.w); a7 += bfhi(v0.w);
        a0 += bflo(v1.x); a1 += bfhi(v1.x); a2 += bflo(v1.y); a3 += bfhi(v1.y);
        a4 += bflo(v1.z); a5 += bfhi(v1.z); a6 += bflo(v1.w); a7 += bfhi(v1.w);
        a0 += bflo(v2.x); a1 += bfhi(v2.x); a2 += bflo(v2.y); a3 += bfhi(v2.y);
        a4 += bflo(v2.z); a5 += bfhi(v2.z); a6 += bflo(v2.w); a7 += bfhi(v2.w);
        a0 += bflo(v3.x); a1 += bfhi(v3.x); a2 += bflo(v3.y); a3 += bfhi(v3.y);
        a4 += bflo(v3.z); a5 += bfhi(v3.z); a6 += bflo(v3.w); a7 += bfhi(v3.w);
    }
    for (; ii < end; ++ii) {
        int li = ii - base0;
        int s = (li < SCAP) ? sidx[li] : csr[ii];
        uint4 v = *(const uint4*)(yq + (size_t)s * FDIM);
        a0 += bflo(v.x); a1 += bfhi(v.x);
        a2 += bflo(v.y); a3 += bfhi(v.y);
        a4 += bflo(v.z); a5 += bfhi(v.z);
        a6 += bflo(v.w); a7 += bfhi(v.w);
    }
    float iv = invd[n];
    uint4 zv = *(const uint4*)(zb + (size_t)n * FDIM + q * 8);
    float r0 = fmaf(a0, iv, bflo(zv.x)), r1 = fmaf(a1, iv, bfhi(zv.x));
    float r2 = fmaf(a2, iv, bflo(zv.y)), r3 = fmaf(a3, iv, bfhi(zv.y));
    float r4 = fmaf(a4, iv, bflo(zv.z)), r5 = fmaf(a5, iv, bfhi(zv.z));
    float r6 = fmaf(a6, iv, bflo(zv.w)), r7 = fmaf(a7, iv, bfhi(zv.w));
    if (RELU) {
        r0 = fmaxf(r0, 0.f); r1 = fmaxf(r1, 0.f); r2 = fmaxf(r2, 0.f); r3 = fmaxf(r3, 0.f);
        r4 = fmaxf(r4, 0.f); r5 = fmaxf(r5, 0.f); r6 = fmaxf(r6, 0.f); r7 = fmaxf(r7, 0.f);
    }
    if (OUTBF) {
        uint4 o;
        o.x = pack2(r0, r1); o.y = pack2(r2, r3);
        o.z = pack2(r4, r5); o.w = pack2(r6, r7);
        *(uint4*)(outb + (size_t)n * FDIM + q * 8) = o;
    } else {
        float* o = outf + (size_t)n * FDIM + q * 8;
        ((float4*)o)[0] = make_float4(r0, r1, r2, r3);
        ((float4*)o)[1] = make_float4(r4, r5, r6, r7);
    }
    if (FUSE4) {
        float rr[8] = {r0, r1, r2, r3, r4, r5, r6, r7};
        float4 py = {0, 0, 0, 0}, pz = {0, 0, 0, 0};
        const float4* wl4 = (const float4*)Wl2;  // [128] rows of 4
        const float4* wr4 = (const float4*)Wr2;
#pragma unroll
        for (int j = 0; j < 8; ++j) {
            float4 wl = wl4[q * 8 + j], wr = wr4[q * 8 + j];
            py.x += rr[j] * wl.x; py.y += rr[j] * wl.y;
            py.z += rr[j] * wl.z; py.w += rr[j] * wl.w;
            pz.x += rr[j] * wr.x; pz.y += rr[j] * wr.y;
            pz.z += rr[j] * wr.z; pz.w += rr[j] * wr.w;
        }
#pragma unroll
        for (int off = 1; off < 16; off <<= 1) {
            py.x += __shfl_xor(py.x, off, 16); py.y += __shfl_xor(py.y, off, 16);
            py.z += __shfl_xor(py.z, off, 16); py.w += __shfl_xor(py.w, off, 16);
            pz.x += __shfl_xor(pz.x, off, 16); pz.y += __shfl_xor(pz.y, off, 16);
            pz.z += __shfl_xor(pz.z, off, 16); pz.w += __shfl_xor(pz.w, off, 16);
        }
        if (q == 0) {
            ((float4*)y4)[n] = py;
            float4 b2 = *(const float4*)bl2;
            float4 o;
            o.x = pz.x + b2.x; o.y = pz.y + b2.y;
            o.z = pz.z + b2.z; o.w = pz.w + b2.w;
            ((float4*)outz)[n] = o;
        }
    }
}

// ================= K5: layer-1 MFMA (bf16 input) ============================
__global__ void __launch_bounds__(256) k_mfma1(
        const u16* __restrict__ in, const uint4* __restrict__ Bp,
        const float* __restrict__ bias, u16* __restrict__ y, u16* __restrict__ zb) {
    __shared__ u16 sA[64 * LPITCH];
    int t = threadIdx.x;
    int blk = blockIdx.x;
    int wave = t >> 6, lane = t & 63, m = lane & 15, quad = lane >> 4;
    {
        int row = t >> 2, q = t & 3;
        int r = blk * 64 + row;
        if (r >= NNODES) r = NNODES - 1;
        const uint4* gsrc = (const uint4*)(in + (size_t)r * FDIM);
        uint4* ldst = (uint4*)(sA + row * LPITCH);
#pragma unroll
        for (int i = 0; i < 4; ++i) ldst[q * 4 + i] = gsrc[q * 4 + i];
    }
    uint4 breg[4][4];
#pragma unroll
    for (int ks = 0; ks < 4; ++ks)
#pragma unroll
        for (int nt = 0; nt < 4; ++nt)
            breg[ks][nt] = Bp[((wave * 4 + nt) * 4 + ks) * 64 + lane];
    __syncthreads();
    bf16x8 a[4][4];
#pragma unroll
    for (int mt = 0; mt < 4; ++mt)
#pragma unroll
        for (int ks = 0; ks < 4; ++ks)
            a[mt][ks] = __builtin_bit_cast(bf16x8,
                *(const uint4*)(sA + (mt * 16 + m) * LPITCH + ks * 32 + quad * 8));
    f32x4 acc[4][4];
#pragma unroll
    for (int mt = 0; mt < 4; ++mt)
#pragma unroll
        for (int nt = 0; nt < 4; ++nt) acc[mt][nt] = (f32x4){0.f, 0.f, 0.f, 0.f};
#pragma unroll
    for (int ks = 0; ks < 4; ++ks)
#pragma unroll
        for (int nt = 0; nt < 4; ++nt) {
            bf16x8 b = __builtin_bit_cast(bf16x8, breg[ks][nt]);
#pragma unroll
            for (int mt = 0; mt < 4; ++mt)
                acc[mt][nt] = __builtin_amdgcn_mfma_f32_16x16x32_bf16(
                    a[mt][ks], b, acc[mt][nt], 0, 0, 0);
        }
    __syncthreads();
    if (wave < 2) {
#pragma unroll
        for (int nt = 0; nt < 4; ++nt) {
            int col = (wave * 4 + nt) * 16 + m;
#pragma unroll
            for (int mt = 0; mt < 4; ++mt)
#pragma unroll
                for (int r = 0; r < 4; ++r)
                    sA[(mt * 16 + quad * 4 + r) * LPITCH + col] = f2bf(acc[mt][nt][r]);
        }
    }
    __syncthreads();
#pragma unroll
    for (int i = 0; i < 4; ++i) {
        int g = i * 256 + t, row = g >> 4, ch = g & 15;
        int gr = blk * 64 + row;
        if (gr < NNODES)
            *((uint4*)(y + (size_t)gr * FDIM) + ch) =
                *(const uint4*)(sA + row * LPITCH + ch * 8);
    }
    __syncthreads();
    if (wave >= 2) {
#pragma unroll
        for (int nt = 0; nt < 4; ++nt) {
            int col = (wave * 4 + nt) * 16 + m - 128;
            float bv = bias[col];
#pragma unroll
            for (int mt = 0; mt < 4; ++mt)
#pragma unroll
                for (int r = 0; r < 4; ++r)
                    sA[(mt * 16 + quad * 4 + r) * LPITCH + col] = f2bf(acc[mt][nt][r] + bv);
        }
    }
    __syncthreads();
#pragma unroll
    for (int i = 0; i < 4; ++i) {
        int g = i * 256 + t, row = g >> 4, ch = g & 15;
        int gr = blk * 64 + row;
        if (gr < NNODES)
            *((uint4*)(zb + (size_t)gr * FDIM) + ch) =
                *(const uint4*)(sA + row * LPITCH + ch * 8);
    }
}

// ================= K7: final 4-wide aggregation + duplicate write ===========
__global__ void k_agg4(const float* __restrict__ y4,
                       const int* __restrict__ offs,
                       const int* __restrict__ csr,
                       const float* __restrict__ invd,
                       float* __restrict__ out) {
    int tid = blockIdx.x * blockDim.x + threadIdx.x;
    int n = tid >> 2, c = tid & 3;
    if (n >= NNODES) return;
    int beg = offs[n], end = offs[n + 1];
    float acc = 0;
    int i = beg;
    for (; i + 4 <= end; i += 4) {
        int s0 = csr[i], s1 = csr[i + 1], s2 = csr[i + 2], s3 = csr[i + 3];
        float v0 = y4[(size_t)s0 * 4 + c];
        float v1 = y4[(size_t)s1 * 4 + c];
        float v2 = y4[(size_t)s2 * 4 + c];
        float v3 = y4[(size_t)s3 * 4 + c];
        acc += v0; acc += v1; acc += v2; acc += v3;
    }
    for (; i < end; ++i) acc += y4[(size_t)csr[i] * 4 + c];
    float r = fmaf(acc, invd[n], out[(size_t)n * 4 + c]);
    out[(size_t)n * 4 + c] = r;
    out[(size_t)NNODES * NCLS + (size_t)n * 4 + c] = r;
}

extern "C" void kernel_launch(void* const* d_in, const int* in_sizes, int n_in,
                              void* d_out, int out_size, void* d_ws, size_t ws_size,
                              hipStream_t stream) {
    const float* x   = (const float*)d_in[0];
    const int* ei    = (const int*)d_in[1];
    const float* Wl0 = (const float*)d_in[2];
    const float* bl0 = (const float*)d_in[3];
    const float* Wr0 = (const float*)d_in[4];
    const float* Wl1 = (const float*)d_in[5];
    const float* bl1 = (const float*)d_in[6];
    const float* Wr1 = (const float*)d_in[7];
    const float* Wl2 = (const float*)d_in[8];
    const float* bl2 = (const float*)d_in[9];
    const float* Wr2 = (const float*)d_in[10];

    const int* src = ei;
    const int* dst = ei + NEDGES;

    float* out = (float*)d_out;
    float* h2  = out + 2 * (size_t)NNODES * NCLS;

    char* ws = (char*)d_ws;
    int*   offs = (int*)(ws + 0);              // 50001 ints
    float* invd = (float*)(ws + 200192);       // N floats
    int*   bcnt = (int*)(ws + 400384);         // NB ints
    int*   bcur = (int*)(ws + 401408);         // NB ints (memset with bcnt)
    int*   csr  = (int*)(ws + 402432);         // E ints
    u16*   y    = (u16*)(ws + 3602432);        // N*128 bf16
    u16*   hb   = (u16*)(ws + 16402432);       // N*128 bf16
    u16*   zb   = (u16*)(ws + 29202432);       // N*128 bf16
    u32*   ebuf = (u32*)hb;                    // E u32 aliases hb: written K2,
                                               // consumed K3; hb first written K4
    float* y4   = (float*)(ws + 42002432);     // N*4 floats
    u16*   Bp0  = (u16*)(ws + 42802432);       // 32768 bf16
    u16*   Bp1  = (u16*)(ws + 42867968);       // 32768 bf16

    hipMemsetAsync(bcnt, 0, 2048, stream);     // bcnt + bcur

    // K1: bucket histogram + pack both layers' weights
    k_pre<<<1038, 256, 0, stream>>>(dst, Wl0, Wr0, Wl1, Wr1, bcnt, Bp0, Bp1);

    // K2: layer-0 MFMA + edge bucket scatter
    k_scatmfma<<<1564, 256, 0, stream>>>(x, (const uint4*)Bp0, bl0, y, zb,
                                         src, dst, bcnt, bcur, ebuf);

    // K3: per-bucket CSR finalize (phase-sorted)
    k_bfinal<<<NB, 256, 0, stream>>>(ebuf, bcnt, offs, invd, csr);

    // K4: layer-0 aggregation (relu, bf16 out)
    k_agg<1, 1, 0><<<NNODES / 16, 256, 0, stream>>>(
        y, offs, csr, invd, zb, hb, nullptr,
        nullptr, nullptr, nullptr, nullptr, nullptr);

    // K5: layer-1 MFMA
    k_mfma1<<<(NNODES + 63) / 64, 256, 0, stream>>>(hb, (const uint4*)Bp1, bl1, y, zb);

    // K6: layer-1 aggregation (fp32 h2 out) + fused final-layer transform
    k_agg<0, 0, 1><<<NNODES / 16, 256, 0, stream>>>(
        y, offs, csr, invd, zb, nullptr, h2,
        Wl2, Wr2, bl2, y4, out);

    // K7: final aggregation, duplicate write
    k_agg4<<<(NNODES * NCLS + 255) / 256, 256, 0, stream>>>(y4, offs, csr, invd, out);
}

// Round 10
// 233.378 us; speedup vs baseline: 19.4484x; 1.0604x over previous
//
#include <hip/hip_runtime.h>
#include <hip/hip_bf16.h>
#include <stdint.h>

#define NNODES 50000
#define NEDGES 800000
#define FDIM   128
#define NCLS   4
#define NB     196        // buckets of 256 nodes
#define ECAP   6144       // LDS edge-stage capacity per bucket (mean 4082)
#define LPITCH 136        // LDS row pitch in u16 (272B)
#define NPH    8          // source phases (src>>13) for gather L2 locality
#define SCAP   768        // LDS csr-slice capacity in k_agg (mean 256)

typedef uint32_t u32;
typedef unsigned char u8;
typedef unsigned short u16;
typedef __bf16 bf16x8 __attribute__((ext_vector_type(8)));
typedef float f32x4 __attribute__((ext_vector_type(4)));
typedef float f32x2 __attribute__((ext_vector_type(2)));

__device__ __forceinline__ u16 f2bf(float f) {
    u32 u = __float_as_uint(f);
    u32 r = u + 0x7fffu + ((u >> 16) & 1u);
    return (u16)(r >> 16);
}
__device__ __forceinline__ u32 pack2(float a, float b) {
    return (u32)f2bf(a) | ((u32)f2bf(b) << 16);
}
__device__ __forceinline__ float bflo(u32 p) { return __uint_as_float(p << 16); }
__device__ __forceinline__ float bfhi(u32 p) { return __uint_as_float(p & 0xffff0000u); }

// 8 bf16 (as uint4 halves) -> 8 fp8 e4m3 packed in uint2 (hardware RNE)
__device__ __forceinline__ uint2 bf8x8_from_bf16(uint4 v) {
    uint2 o;
    o.x = __builtin_amdgcn_cvt_pk_fp8_f32(bflo(v.x), bfhi(v.x), 0,   false);
    o.x = __builtin_amdgcn_cvt_pk_fp8_f32(bflo(v.y), bfhi(v.y), o.x, true);
    o.y = __builtin_amdgcn_cvt_pk_fp8_f32(bflo(v.z), bfhi(v.z), 0,   false);
    o.y = __builtin_amdgcn_cvt_pk_fp8_f32(bflo(v.w), bfhi(v.w), o.y, true);
    return o;
}

// ================= K1: bucket histogram + both weight packs =================
__global__ void __launch_bounds__(256) k_pre(
        const int* __restrict__ dst,
        const float* __restrict__ Wl0, const float* __restrict__ Wr0,
        const float* __restrict__ Wl1, const float* __restrict__ Wr1,
        int* __restrict__ bcnt, u16* __restrict__ Bp0, u16* __restrict__ Bp1) {
    int t = threadIdx.x;
    int bid = blockIdx.x;
    if (bid < 782) {                 // ---- bhist ----
        __shared__ int h[NB];
        if (t < NB) h[t] = 0;
        __syncthreads();
        int base = bid * 1024;
#pragma unroll
        for (int i = 0; i < 4; ++i) {
            int e = base + i * 256 + t;
            if (e < NEDGES) atomicAdd(&h[dst[e] >> 8], 1);
        }
        __syncthreads();
        if (t < NB) {
            int v = h[t];
            if (v) atomicAdd(&bcnt[t], v);
        }
    } else {                          // ---- weight pack (128 blocks per layer) ----
        int layer = (bid < 910) ? 0 : 1;
        int pid = bid - (layer ? 910 : 782);
        int tid = pid * 256 + t;      // 0..32767
        int j    = tid & 7;
        int lane = (tid >> 3) & 63;
        int ks   = (tid >> 9) & 3;
        int nt   = tid >> 11;
        int col  = nt * 16 + (lane & 15);
        int k    = ks * 32 + (lane >> 4) * 8 + j;
        const float* Wl = layer ? Wl1 : Wl0;
        const float* Wr = layer ? Wr1 : Wr0;
        float v = (col < FDIM) ? Wl[k * FDIM + col] : Wr[k * FDIM + (col - FDIM)];
        (layer ? Bp1 : Bp0)[tid] = f2bf(v);
    }
}

// ============ K2: layer-0 MFMA (blocks 0..781) + edge scatter (782..1563) ===
// y written as fp8 e4m3 (128 B/row); zb stays bf16.
// ebuf aliases hb (first written in K4) — must NOT alias y/zb.
__global__ void __launch_bounds__(256) k_scatmfma(
        const float* __restrict__ x, const uint4* __restrict__ Bp,
        const float* __restrict__ bias, u8* __restrict__ y, u16* __restrict__ zb,
        const int* __restrict__ src, const int* __restrict__ dst,
        const int* __restrict__ bcnt, int* __restrict__ bcur,
        u32* __restrict__ ebuf) {
    __shared__ u16 sA[64 * LPITCH];   // 17408 B; scatter half aliases ints onto it
    int t = threadIdx.x;
    if (blockIdx.x < 782) {
        // ---------------- MFMA dual GEMM, layer 0 (fp32 input) ----------------
        int blk = blockIdx.x;
        int wave = t >> 6, lane = t & 63, m = lane & 15, quad = lane >> 4;
        {
            int row = t >> 2, q = t & 3;
            int r = blk * 64 + row;
            if (r >= NNODES) r = NNODES - 1;
            const float4* gs = (const float4*)(x + (size_t)r * FDIM) + q * 8;
            uint4* ld = (uint4*)(sA + row * LPITCH + q * 32);
#pragma unroll
            for (int i = 0; i < 4; ++i) {
                float4 a = gs[2 * i], b = gs[2 * i + 1];
                uint4 v;
                v.x = pack2(a.x, a.y); v.y = pack2(a.z, a.w);
                v.z = pack2(b.x, b.y); v.w = pack2(b.z, b.w);
                ld[i] = v;
            }
        }
        uint4 breg[4][4];
#pragma unroll
        for (int ks = 0; ks < 4; ++ks)
#pragma unroll
            for (int nt = 0; nt < 4; ++nt)
                breg[ks][nt] = Bp[((wave * 4 + nt) * 4 + ks) * 64 + lane];
        __syncthreads();
        bf16x8 a[4][4];
#pragma unroll
        for (int mt = 0; mt < 4; ++mt)
#pragma unroll
            for (int ks = 0; ks < 4; ++ks)
                a[mt][ks] = __builtin_bit_cast(bf16x8,
                    *(const uint4*)(sA + (mt * 16 + m) * LPITCH + ks * 32 + quad * 8));
        f32x4 acc[4][4];
#pragma unroll
        for (int mt = 0; mt < 4; ++mt)
#pragma unroll
            for (int nt = 0; nt < 4; ++nt) acc[mt][nt] = (f32x4){0.f, 0.f, 0.f, 0.f};
#pragma unroll
        for (int ks = 0; ks < 4; ++ks)
#pragma unroll
            for (int nt = 0; nt < 4; ++nt) {
                bf16x8 b = __builtin_bit_cast(bf16x8, breg[ks][nt]);
#pragma unroll
                for (int mt = 0; mt < 4; ++mt)
                    acc[mt][nt] = __builtin_amdgcn_mfma_f32_16x16x32_bf16(
                        a[mt][ks], b, acc[mt][nt], 0, 0, 0);
            }
        __syncthreads();
        if (wave < 2) {
#pragma unroll
            for (int nt = 0; nt < 4; ++nt) {
                int col = (wave * 4 + nt) * 16 + m;
#pragma unroll
                for (int mt = 0; mt < 4; ++mt)
#pragma unroll
                    for (int r = 0; r < 4; ++r)
                        sA[(mt * 16 + quad * 4 + r) * LPITCH + col] = f2bf(acc[mt][nt][r]);
            }
        }
        __syncthreads();
#pragma unroll
        for (int i = 0; i < 4; ++i) {
            int g = i * 256 + t, row = g >> 4, ch = g & 15;
            int gr = blk * 64 + row;
            if (gr < NNODES) {
                uint4 v = *(const uint4*)(sA + row * LPITCH + ch * 8);
                *((uint2*)(y + (size_t)gr * FDIM) + ch) = bf8x8_from_bf16(v);
            }
        }
        __syncthreads();
        if (wave >= 2) {
#pragma unroll
            for (int nt = 0; nt < 4; ++nt) {
                int col = (wave * 4 + nt) * 16 + m - 128;
                float bv = bias[col];
#pragma unroll
                for (int mt = 0; mt < 4; ++mt)
#pragma unroll
                    for (int r = 0; r < 4; ++r)
                        sA[(mt * 16 + quad * 4 + r) * LPITCH + col] = f2bf(acc[mt][nt][r] + bv);
            }
        }
        __syncthreads();
#pragma unroll
        for (int i = 0; i < 4; ++i) {
            int g = i * 256 + t, row = g >> 4, ch = g & 15;
            int gr = blk * 64 + row;
            if (gr < NNODES)
                *((uint4*)(zb + (size_t)gr * FDIM) + ch) =
                    *(const uint4*)(sA + row * LPITCH + ch * 8);
        }
    } else {
        // ---------------- edge bucket scatter (with in-LDS bucket scan) -------
        int* hh = (int*)sA;           // [256]
        int* bb = hh + 256;           // [256]
        int* ss = bb + 256;           // [256]
        int v = (t < NB) ? bcnt[t] : 0;
        ss[t] = v;
        __syncthreads();
        for (int off = 1; off < 256; off <<= 1) {
            int u = (t >= off) ? ss[t - off] : 0;
            __syncthreads();
            ss[t] += u;
            __syncthreads();
        }
        int boff = ss[t] - v;         // exclusive bucket start
        hh[t] = 0;
        __syncthreads();
        int eb = (blockIdx.x - 782) * 1024;
        int mb[4];
        u32 pk[4];
#pragma unroll
        for (int i = 0; i < 4; ++i) {
            int e = eb + i * 256 + t;
            if (e < NEDGES) {
                int d = dst[e];
                mb[i] = d >> 8;
                pk[i] = (u32)src[e] | ((u32)d << 16);
                atomicAdd(&hh[mb[i]], 1);
            } else mb[i] = -1;
        }
        __syncthreads();
        if (t < NB) {
            int c = hh[t];
            bb[t] = c ? (boff + atomicAdd(&bcur[t], c)) : 0;
            hh[t] = 0;
        }
        __syncthreads();
#pragma unroll
        for (int i = 0; i < 4; ++i) {
            if (mb[i] >= 0) {
                int r = atomicAdd(&hh[mb[i]], 1);
                ebuf[bb[mb[i]] + r] = pk[i];
            }
        }
    }
}

// ======= K3: per-bucket CSR finalize, phase-sorted (self-scans bcnt) ========
__global__ void __launch_bounds__(256) k_bfinal(
        const u32* __restrict__ ebuf, const int* __restrict__ bcnt,
        int* __restrict__ offs, float* __restrict__ invd, int* __restrict__ csr) {
    __shared__ u32 se[ECAP];
    __shared__ int deg8[256 * NPH];
    __shared__ int s[256];
    int b = blockIdx.x, t = threadIdx.x;
    int nbase = b << 8;
    int v = (t < NB) ? bcnt[t] : 0;
    s[t] = v;
    __syncthreads();
    for (int off = 1; off < 256; off <<= 1) {
        int u = (t >= off) ? s[t - off] : 0;
        __syncthreads();
        s[t] += u;
        __syncthreads();
    }
    int ebeg = s[b] - bcnt[b];
    int ecnt = bcnt[b];
    __syncthreads();
#pragma unroll
    for (int j = 0; j < NPH; ++j) deg8[t * NPH + j] = 0;
    __syncthreads();
    for (int i = t; i < ecnt; i += 256) {
        u32 e = ebuf[ebeg + i];
        if (i < ECAP) se[i] = e;
        atomicAdd(&deg8[((int)(e >> 16) - nbase) * NPH + (((int)(e & 0xffffu)) >> 13)], 1);
    }
    __syncthreads();
    int pre[NPH];
    int run = 0;
#pragma unroll
    for (int j = 0; j < NPH; ++j) { pre[j] = run; run += deg8[t * NPH + j]; }
    int d = run;
    s[t] = d;
    __syncthreads();
    for (int off = 1; off < 256; off <<= 1) {
        int u = (t >= off) ? s[t - off] : 0;
        __syncthreads();
        s[t] += u;
        __syncthreads();
    }
    int ex = s[t] - d;
    int node = nbase + t;
    if (node < NNODES) {
        offs[node] = ebeg + ex;
        invd[node] = (d > 0) ? (1.0f / (float)d) : 0.0f;
    }
    __syncthreads();
#pragma unroll
    for (int j = 0; j < NPH; ++j) deg8[t * NPH + j] = ex + pre[j];
    __syncthreads();
    for (int i = t; i < ecnt; i += 256) {
        u32 e = (i < ECAP) ? se[i] : ebuf[ebeg + i];
        int dl = (int)(e >> 16) - nbase;
        int sv = (int)(e & 0xffffu);
        int r = atomicAdd(&deg8[dl * NPH + (sv >> 13)], 1);
        csr[ebeg + r] = sv;
    }
    if (b == 0 && t == 0) offs[NNODES] = NEDGES;
}

// ===== K4/K6: gather aggregation (+ optional fused final-layer transform) ===
// y rows are fp8 e4m3 (128 B); unroll x4 for MLP; fp8->f32 via HW cvt.
template <int RELU, int OUTBF, int FUSE4>
__global__ void __launch_bounds__(256) k_agg(
        const u8* __restrict__ y, const int* __restrict__ offs,
        const int* __restrict__ csr, const float* __restrict__ invd,
        const u16* __restrict__ zb, u16* __restrict__ outb, float* __restrict__ outf,
        const float* __restrict__ Wl2, const float* __restrict__ Wr2,
        const float* __restrict__ bl2, float* __restrict__ y4,
        float* __restrict__ outz) {
    __shared__ int sidx[SCAP];
    int t = threadIdx.x;
    int n0 = blockIdx.x * 16;
    int base0 = offs[n0];
    int ecnt = offs[n0 + 16] - base0;
    for (int i = t; i < ecnt && i < SCAP; i += 256) sidx[i] = csr[base0 + i];
    __syncthreads();
    int nl = t >> 4, q = t & 15;
    int n = n0 + nl;
    int beg = offs[n], end = offs[n + 1];
    float a0 = 0, a1 = 0, a2 = 0, a3 = 0, a4 = 0, a5 = 0, a6 = 0, a7 = 0;
    const u8* yq = y + q * 8;
    int ii = beg;
    for (; ii + 4 <= end; ii += 4) {
        int li = ii - base0;
        int s0, s1, s2, s3;
        if (li + 3 < SCAP) {
            s0 = sidx[li]; s1 = sidx[li + 1]; s2 = sidx[li + 2]; s3 = sidx[li + 3];
        } else {
            s0 = csr[ii]; s1 = csr[ii + 1]; s2 = csr[ii + 2]; s3 = csr[ii + 3];
        }
        uint2 v0 = *(const uint2*)(yq + (size_t)s0 * FDIM);
        uint2 v1 = *(const uint2*)(yq + (size_t)s1 * FDIM);
        uint2 v2 = *(const uint2*)(yq + (size_t)s2 * FDIM);
        uint2 v3 = *(const uint2*)(yq + (size_t)s3 * FDIM);
#pragma unroll
        for (int j = 0; j < 4; ++j) {
            uint2 v = (j == 0) ? v0 : (j == 1) ? v1 : (j == 2) ? v2 : v3;
            f32x2 p0 = __builtin_amdgcn_cvt_pk_f32_fp8(v.x, false);
            f32x2 p1 = __builtin_amdgcn_cvt_pk_f32_fp8(v.x, true);
            f32x2 p2 = __builtin_amdgcn_cvt_pk_f32_fp8(v.y, false);
            f32x2 p3 = __builtin_amdgcn_cvt_pk_f32_fp8(v.y, true);
            a0 += p0.x; a1 += p0.y; a2 += p1.x; a3 += p1.y;
            a4 += p2.x; a5 += p2.y; a6 += p3.x; a7 += p3.y;
        }
    }
    for (; ii < end; ++ii) {
        int li = ii - base0;
        int s = (li < SCAP) ? sidx[li] : csr[ii];
        uint2 v = *(const uint2*)(yq + (size_t)s * FDIM);
        f32x2 p0 = __builtin_amdgcn_cvt_pk_f32_fp8(v.x, false);
        f32x2 p1 = __builtin_amdgcn_cvt_pk_f32_fp8(v.x, true);
        f32x2 p2 = __builtin_amdgcn_cvt_pk_f32_fp8(v.y, false);
        f32x2 p3 = __builtin_amdgcn_cvt_pk_f32_fp8(v.y, true);
        a0 += p0.x; a1 += p0.y; a2 += p1.x; a3 += p1.y;
        a4 += p2.x; a5 += p2.y; a6 += p3.x; a7 += p3.y;
    }
    float iv = invd[n];
    uint4 zv = *(const uint4*)(zb + (size_t)n * FDIM + q * 8);
    float r0 = fmaf(a0, iv, bflo(zv.x)), r1 = fmaf(a1, iv, bfhi(zv.x));
    float r2 = fmaf(a2, iv, bflo(zv.y)), r3 = fmaf(a3, iv, bfhi(zv.y));
    float r4 = fmaf(a4, iv, bflo(zv.z)), r5 = fmaf(a5, iv, bfhi(zv.z));
    float r6 = fmaf(a6, iv, bflo(zv.w)), r7 = fmaf(a7, iv, bfhi(zv.w));
    if (RELU) {
        r0 = fmaxf(r0, 0.f); r1 = fmaxf(r1, 0.f); r2 = fmaxf(r2, 0.f); r3 = fmaxf(r3, 0.f);
        r4 = fmaxf(r4, 0.f); r5 = fmaxf(r5, 0.f); r6 = fmaxf(r6, 0.f); r7 = fmaxf(r7, 0.f);
    }
    if (OUTBF) {
        uint4 o;
        o.x = pack2(r0, r1); o.y = pack2(r2, r3);
        o.z = pack2(r4, r5); o.w = pack2(r6, r7);
        *(uint4*)(outb + (size_t)n * FDIM + q * 8) = o;
    } else {
        float* o = outf + (size_t)n * FDIM + q * 8;
        ((float4*)o)[0] = make_float4(r0, r1, r2, r3);
        ((float4*)o)[1] = make_float4(r4, r5, r6, r7);
    }
    if (FUSE4) {
        float rr[8] = {r0, r1, r2, r3, r4, r5, r6, r7};
        float4 py = {0, 0, 0, 0}, pz = {0, 0, 0, 0};
        const float4* wl4 = (const float4*)Wl2;  // [128] rows of 4
        const float4* wr4 = (const float4*)Wr2;
#pragma unroll
        for (int j = 0; j < 8; ++j) {
            float4 wl = wl4[q * 8 + j], wr = wr4[q * 8 + j];
            py.x += rr[j] * wl.x; py.y += rr[j] * wl.y;
            py.z += rr[j] * wl.z; py.w += rr[j] * wl.w;
            pz.x += rr[j] * wr.x; pz.y += rr[j] * wr.y;
            pz.z += rr[j] * wr.z; pz.w += rr[j] * wr.w;
        }
#pragma unroll
        for (int off = 1; off < 16; off <<= 1) {
            py.x += __shfl_xor(py.x, off, 16); py.y += __shfl_xor(py.y, off, 16);
            py.z += __shfl_xor(py.z, off, 16); py.w += __shfl_xor(py.w, off, 16);
            pz.x += __shfl_xor(pz.x, off, 16); pz.y += __shfl_xor(pz.y, off, 16);
            pz.z += __shfl_xor(pz.z, off, 16); pz.w += __shfl_xor(pz.w, off, 16);
        }
        if (q == 0) {
            ((float4*)y4)[n] = py;
            float4 b2 = *(const float4*)bl2;
            float4 o;
            o.x = pz.x + b2.x; o.y = pz.y + b2.y;
            o.z = pz.z + b2.z; o.w = pz.w + b2.w;
            ((float4*)outz)[n] = o;
        }
    }
}

// ================= K5: layer-1 MFMA (bf16 input, fp8 y out) =================
__global__ void __launch_bounds__(256) k_mfma1(
        const u16* __restrict__ in, const uint4* __restrict__ Bp,
        const float* __restrict__ bias, u8* __restrict__ y, u16* __restrict__ zb) {
    __shared__ u16 sA[64 * LPITCH];
    int t = threadIdx.x;
    int blk = blockIdx.x;
    int wave = t >> 6, lane = t & 63, m = lane & 15, quad = lane >> 4;
    {
        int row = t >> 2, q = t & 3;
        int r = blk * 64 + row;
        if (r >= NNODES) r = NNODES - 1;
        const uint4* gsrc = (const uint4*)(in + (size_t)r * FDIM);
        uint4* ldst = (uint4*)(sA + row * LPITCH);
#pragma unroll
        for (int i = 0; i < 4; ++i) ldst[q * 4 + i] = gsrc[q * 4 + i];
    }
    uint4 breg[4][4];
#pragma unroll
    for (int ks = 0; ks < 4; ++ks)
#pragma unroll
        for (int nt = 0; nt < 4; ++nt)
            breg[ks][nt] = Bp[((wave * 4 + nt) * 4 + ks) * 64 + lane];
    __syncthreads();
    bf16x8 a[4][4];
#pragma unroll
    for (int mt = 0; mt < 4; ++mt)
#pragma unroll
        for (int ks = 0; ks < 4; ++ks)
            a[mt][ks] = __builtin_bit_cast(bf16x8,
                *(const uint4*)(sA + (mt * 16 + m) * LPITCH + ks * 32 + quad * 8));
    f32x4 acc[4][4];
#pragma unroll
    for (int mt = 0; mt < 4; ++mt)
#pragma unroll
        for (int nt = 0; nt < 4; ++nt) acc[mt][nt] = (f32x4){0.f, 0.f, 0.f, 0.f};
#pragma unroll
    for (int ks = 0; ks < 4; ++ks)
#pragma unroll
        for (int nt = 0; nt < 4; ++nt) {
            bf16x8 b = __builtin_bit_cast(bf16x8, breg[ks][nt]);
#pragma unroll
            for (int mt = 0; mt < 4; ++mt)
                acc[mt][nt] = __builtin_amdgcn_mfma_f32_16x16x32_bf16(
                    a[mt][ks], b, acc[mt][nt], 0, 0, 0);
        }
    __syncthreads();
    if (wave < 2) {
#pragma unroll
        for (int nt = 0; nt < 4; ++nt) {
            int col = (wave * 4 + nt) * 16 + m;
#pragma unroll
            for (int mt = 0; mt < 4; ++mt)
#pragma unroll
                for (int r = 0; r < 4; ++r)
                    sA[(mt * 16 + quad * 4 + r) * LPITCH + col] = f2bf(acc[mt][nt][r]);
        }
    }
    __syncthreads();
#pragma unroll
    for (int i = 0; i < 4; ++i) {
        int g = i * 256 + t, row = g >> 4, ch = g & 15;
        int gr = blk * 64 + row;
        if (gr < NNODES) {
            uint4 v = *(const uint4*)(sA + row * LPITCH + ch * 8);
            *((uint2*)(y + (size_t)gr * FDIM) + ch) = bf8x8_from_bf16(v);
        }
    }
    __syncthreads();
    if (wave >= 2) {
#pragma unroll
        for (int nt = 0; nt < 4; ++nt) {
            int col = (wave * 4 + nt) * 16 + m - 128;
            float bv = bias[col];
#pragma unroll
            for (int mt = 0; mt < 4; ++mt)
#pragma unroll
                for (int r = 0; r < 4; ++r)
                    sA[(mt * 16 + quad * 4 + r) * LPITCH + col] = f2bf(acc[mt][nt][r] + bv);
        }
    }
    __syncthreads();
#pragma unroll
    for (int i = 0; i < 4; ++i) {
        int g = i * 256 + t, row = g >> 4, ch = g & 15;
        int gr = blk * 64 + row;
        if (gr < NNODES)
            *((uint4*)(zb + (size_t)gr * FDIM) + ch) =
                *(const uint4*)(sA + row * LPITCH + ch * 8);
    }
}

// ================= K7: final 4-wide aggregation + duplicate write ===========
__global__ void k_agg4(const float* __restrict__ y4,
                       const int* __restrict__ offs,
                       const int* __restrict__ csr,
                       const float* __restrict__ invd,
                       float* __restrict__ out) {
    int tid = blockIdx.x * blockDim.x + threadIdx.x;
    int n = tid >> 2, c = tid & 3;
    if (n >= NNODES) return;
    int beg = offs[n], end = offs[n + 1];
    float acc = 0;
    int i = beg;
    for (; i + 4 <= end; i += 4) {
        int s0 = csr[i], s1 = csr[i + 1], s2 = csr[i + 2], s3 = csr[i + 3];
        float v0 = y4[(size_t)s0 * 4 + c];
        float v1 = y4[(size_t)s1 * 4 + c];
        float v2 = y4[(size_t)s2 * 4 + c];
        float v3 = y4[(size_t)s3 * 4 + c];
        acc += v0; acc += v1; acc += v2; acc += v3;
    }
    for (; i < end; ++i) acc += y4[(size_t)csr[i] * 4 + c];
    float r = fmaf(acc, invd[n], out[(size_t)n * 4 + c]);
    out[(size_t)n * 4 + c] = r;
    out[(size_t)NNODES * NCLS + (size_t)n * 4 + c] = r;
}

extern "C" void kernel_launch(void* const* d_in, const int* in_sizes, int n_in,
                              void* d_out, int out_size, void* d_ws, size_t ws_size,
                              hipStream_t stream) {
    const float* x   = (const float*)d_in[0];
    const int* ei    = (const int*)d_in[1];
    const float* Wl0 = (const float*)d_in[2];
    const float* bl0 = (const float*)d_in[3];
    const float* Wr0 = (const float*)d_in[4];
    const float* Wl1 = (const float*)d_in[5];
    const float* bl1 = (const float*)d_in[6];
    const float* Wr1 = (const float*)d_in[7];
    const float* Wl2 = (const float*)d_in[8];
    const float* bl2 = (const float*)d_in[9];
    const float* Wr2 = (const float*)d_in[10];

    const int* src = ei;
    const int* dst = ei + NEDGES;

    float* out = (float*)d_out;
    float* h2  = out + 2 * (size_t)NNODES * NCLS;

    char* ws = (char*)d_ws;
    int*   offs = (int*)(ws + 0);              // 50001 ints
    float* invd = (float*)(ws + 200192);       // N floats
    int*   bcnt = (int*)(ws + 400384);         // NB ints
    int*   bcur = (int*)(ws + 401408);         // NB ints (memset with bcnt)
    int*   csr  = (int*)(ws + 402432);         // E ints
    u8*    y    = (u8*)(ws + 3602432);         // N*128 fp8 e4m3 (6.4 MB)
    u16*   hb   = (u16*)(ws + 16402432);       // N*128 bf16
    u16*   zb   = (u16*)(ws + 29202432);       // N*128 bf16
    u32*   ebuf = (u32*)hb;                    // E u32 aliases hb: written K2,
                                               // consumed K3; hb first written K4
    float* y4   = (float*)(ws + 42002432);     // N*4 floats
    u16*   Bp0  = (u16*)(ws + 42802432);       // 32768 bf16
    u16*   Bp1  = (u16*)(ws + 42867968);       // 32768 bf16

    hipMemsetAsync(bcnt, 0, 2048, stream);     // bcnt + bcur

    // K1: bucket histogram + pack both layers' weights
    k_pre<<<1038, 256, 0, stream>>>(dst, Wl0, Wr0, Wl1, Wr1, bcnt, Bp0, Bp1);

    // K2: layer-0 MFMA + edge bucket scatter
    k_scatmfma<<<1564, 256, 0, stream>>>(x, (const uint4*)Bp0, bl0, y, zb,
                                         src, dst, bcnt, bcur, ebuf);

    // K3: per-bucket CSR finalize (phase-sorted)
    k_bfinal<<<NB, 256, 0, stream>>>(ebuf, bcnt, offs, invd, csr);

    // K4: layer-0 aggregation (relu, bf16 out)
    k_agg<1, 1, 0><<<NNODES / 16, 256, 0, stream>>>(
        y, offs, csr, invd, zb, hb, nullptr,
        nullptr, nullptr, nullptr, nullptr, nullptr);

    // K5: layer-1 MFMA
    k_mfma1<<<(NNODES + 63) / 64, 256, 0, stream>>>(hb, (const uint4*)Bp1, bl1, y, zb);

    // K6: layer-1 aggregation (fp32 h2 out) + fused final-layer transform
    k_agg<0, 0, 1><<<NNODES / 16, 256, 0, stream>>>(
        y, offs, csr, invd, zb, nullptr, h2,
        Wl2, Wr2, bl2, y4, out);

    // K7: final aggregation, duplicate write
    k_agg4<<<(NNODES * NCLS + 255) / 256, 256, 0, stream>>>(y4, offs, csr, invd, out);
}